// Round 8
// baseline (527.077 us; speedup 1.0000x reference)
//
#include <hip/hip_runtime.h>
#include <stdint.h>

#define BB   4
#define TT   2048
#define DD   512
#define FFF  2048
#define NEXP 4
#define NTOK (BB*TT)
#define LNEPS 1e-5f

typedef unsigned short u16;
typedef __attribute__((ext_vector_type(8))) short bf16x8;  // 8 bf16 (4 VGPRs)
typedef __attribute__((ext_vector_type(4))) float f32x4;   // 4 f32 acc

__device__ __forceinline__ u16 f2bf(float f) {
  union { float f; unsigned u; } v; v.f = f;
  return (u16)((v.u + 0x7FFFu + ((v.u >> 16) & 1u)) >> 16);  // RNE
}
__device__ __forceinline__ float bf2f(u16 h) {
  union { unsigned u; float f; } v; v.u = (unsigned)h << 16; return v.f;
}

// async 16B/lane global->LDS DMA. LDS dest = wave-uniform base + lane*16.
__device__ __forceinline__ void gl2lds(const u16* g, u16* l) {
  __builtin_amdgcn_global_load_lds(
      (const __attribute__((address_space(1))) void*)g,
      (__attribute__((address_space(3))) void*)l, 16, 0, 0);
}
__device__ __forceinline__ void gl2lds_f(const float* g, float* l) {
  __builtin_amdgcn_global_load_lds(
      (const __attribute__((address_space(1))) void*)g,
      (__attribute__((address_space(3))) void*)l, 16, 0, 0);
}

// packed f32x2 -> bf16x2 (RNE), gfx950 [T12/m240: no builtin, inline asm]
__device__ __forceinline__ unsigned cvtpk_bf16(float a, float b) {
  unsigned r;
  asm volatile("v_cvt_pk_bf16_f32 %0, %1, %2" : "=v"(r) : "v"(a), "v"(b));
  return r;
}
// split 8 f32 -> (hi, lo) bf16x8, RNE both levels (matches split_f32_kernel numerics)
__device__ __forceinline__ void split2x4(f32x4 a0, f32x4 a1, bf16x8* hi, bf16x8* lo) {
  union U { unsigned u[4]; bf16x8 v; };
  U H, L;
  H.u[0] = cvtpk_bf16(a0[0], a0[1]);
  H.u[1] = cvtpk_bf16(a0[2], a0[3]);
  H.u[2] = cvtpk_bf16(a1[0], a1[1]);
  H.u[3] = cvtpk_bf16(a1[2], a1[3]);
  union F { unsigned u; float f; } t0, t1;
  float l0,l1,l2,l3,l4,l5,l6,l7;
  t0.u = H.u[0] << 16;         l0 = a0[0] - t0.f;
  t1.u = H.u[0] & 0xffff0000u; l1 = a0[1] - t1.f;
  t0.u = H.u[1] << 16;         l2 = a0[2] - t0.f;
  t1.u = H.u[1] & 0xffff0000u; l3 = a0[3] - t1.f;
  t0.u = H.u[2] << 16;         l4 = a1[0] - t0.f;
  t1.u = H.u[2] & 0xffff0000u; l5 = a1[1] - t1.f;
  t0.u = H.u[3] << 16;         l6 = a1[2] - t0.f;
  t1.u = H.u[3] & 0xffff0000u; l7 = a1[3] - t1.f;
  L.u[0] = cvtpk_bf16(l0, l1);
  L.u[1] = cvtpk_bf16(l2, l3);
  L.u[2] = cvtpk_bf16(l4, l5);
  L.u[3] = cvtpk_bf16(l6, l7);
  *hi = H.v; *lo = L.v;
}

// ---- LDS bank-conflict fix (T2, rule #21), verified R5 (conflicts 4.26M -> 0):
// gl2lds writes linearly, so we pre-swizzle the GLOBAL source K-chunk per lane and
// XOR the same term on the ds_read side. bf16 tiles: physical (row, c) holds
// logical (row, c ^ ((row>>1)&3)).
//   staging: ac1 = ((tid&3) ^ ((tid>>3)&3)) << 3
//   read:    chunk_off = quad*8 ^ (((l16>>1)&3)<<3)
// f32 tiles (fbv A): 8x 16B chunks/row, phys_chunk = logical ^ (row&7).

// ---------------- elementwise split f32 -> (hi, lo) bf16 ----------------
__global__ void split_f32_kernel(const float* __restrict__ in, u16* __restrict__ hi,
                                 u16* __restrict__ lo, int n4) {
  int i = blockIdx.x * blockDim.x + threadIdx.x;
  if (i >= n4) return;
  float4 f = ((const float4*)in)[i];
  u16 h0 = f2bf(f.x), h1 = f2bf(f.y), h2 = f2bf(f.z), h3 = f2bf(f.w);
  u16 l0 = f2bf(f.x - bf2f(h0)), l1 = f2bf(f.y - bf2f(h1));
  u16 l2 = f2bf(f.z - bf2f(h2)), l3 = f2bf(f.w - bf2f(h3));
  ((uint2*)hi)[i] = uint2{(unsigned)h0 | ((unsigned)h1 << 16), (unsigned)h2 | ((unsigned)h3 << 16)};
  ((uint2*)lo)[i] = uint2{(unsigned)l0 | ((unsigned)l1 << 16), (unsigned)l2 | ((unsigned)l3 << 16)};
}

// ------- fused 3x square transpose+split (Wk, Wv, Wo), z selects matrix -------
__global__ void transpose_split3_kernel(const float* __restrict__ s0, const float* __restrict__ s1,
                                        const float* __restrict__ s2,
                                        u16* __restrict__ kvhi, u16* __restrict__ kvlo,
                                        u16* __restrict__ ohi,  u16* __restrict__ olo) {
  __shared__ float tile[32][33];
  const int z = blockIdx.z;
  const float* in = (z == 0) ? s0 : (z == 1) ? s1 : s2;
  int c0 = blockIdx.x * 32, r0 = blockIdx.y * 32;
  int tx = threadIdx.x, ty = threadIdx.y;
#pragma unroll
  for (int k = 0; k < 4; k++)
    tile[ty + 8*k][tx] = in[(size_t)(r0 + ty + 8*k) * DD + c0 + tx];
  __syncthreads();
#pragma unroll
  for (int k = 0; k < 4; k++) {
    float v = tile[tx][ty + 8*k];
    u16 h = f2bf(v);
    u16 l = f2bf(v - bf2f(h));
    const int c = c0 + ty + 8*k;
    if (z < 2) {
      size_t idx = (size_t)(2*c + z) * DD + r0 + tx;
      kvhi[idx] = h; kvlo[idx] = l;
    } else {
      size_t idx = (size_t)c * DD + r0 + tx;
      ohi[idx] = h; olo[idx] = l;
    }
  }
}

// ------------- transpose + cast: f32 [Z][R][C] -> bf16 [Z][C][R] (MoE weights) -------------
__global__ void transpose_cast_kernel(const float* __restrict__ in, u16* __restrict__ out,
                                      int R, int C) {
  __shared__ float tile[32][33];
  int z = blockIdx.z;
  in  += (size_t)z * R * C;
  out += (size_t)z * R * C;
  int c0 = blockIdx.x * 32, r0 = blockIdx.y * 32;
  int tx = threadIdx.x, ty = threadIdx.y;
#pragma unroll
  for (int k = 0; k < 4; k++)
    tile[ty + 8*k][tx] = in[(size_t)(r0 + ty + 8*k) * C + c0 + tx];
  __syncthreads();
#pragma unroll
  for (int k = 0; k < 4; k++)
    out[(size_t)(c0 + ty + 8*k) * R + r0 + tx] = f2bf(tile[tx][ty + 8*k]);
}

// ---------------- split-bf16 GEMM (BM=128, BN=64), modes 0/1 ----------------
// MODE 0: out0[row*N+col] = v + bias0[col]. grid(mt,nt), 2-barrier 1-buf (short K).
// MODE 1: fused KV: interleaved cols (2d=K_d, 2d+1=V_d). Epilogue computes
//         kv_sum atomics (out0=kvs) and writes V^T hi/lo (outh/outl, [B][D][T]).
template<int MODE>
__global__ __launch_bounds__(256)
void gemm_split2_kernel(const u16* __restrict__ Ahi, const u16* __restrict__ Alo,
                        const u16* __restrict__ Bhi, const u16* __restrict__ Blo,
                        const float* __restrict__ bias0, const float* __restrict__ bias1,
                        float* __restrict__ out0,
                        u16* __restrict__ outh, u16* __restrict__ outl,
                        int M, int N, int K,
                        long long sA, long long sB, long long sO) {
  __shared__ u16 AhL[128*32], AlL[128*32];
  __shared__ u16 BhL[64*32],  BlL[64*32];

  const int mt = blockIdx.x, nt = blockIdx.y, z = blockIdx.z;
  const int m0 = mt * 128, n0 = nt * 64;

  Ahi += (size_t)z * sA; Alo += (size_t)z * sA;
  Bhi += (size_t)z * sB; Blo += (size_t)z * sB;
  const int tid = threadIdx.x;
  const int lane = tid & 63, wave = tid >> 6;
  const int wm = wave >> 1, wn = wave & 1;
  const int quad = lane >> 4, l16 = lane & 15;
  const int sxor = ((l16 >> 1) & 3) << 3;      // read-side chunk XOR (u16 units)

  const int ar1 = tid >> 2;
  const int ac1 = (((tid & 3) ^ ((tid >> 3) & 3)) << 3);   // swizzled source chunk
  const u16* pAh1 = Ahi + (size_t)(m0 + ar1) * K + ac1;
  const u16* pAh2 = Ahi + (size_t)(m0 + ar1 + 64) * K + ac1;
  const u16* pAl1 = Alo + (size_t)(m0 + ar1) * K + ac1;
  const u16* pAl2 = Alo + (size_t)(m0 + ar1 + 64) * K + ac1;
  const u16* pBh1 = Bhi + (size_t)(n0 + ar1) * K + ac1;
  const u16* pBl1 = Blo + (size_t)(n0 + ar1) * K + ac1;
  const int wofs = wave * 512;

  f32x4 acc[4][2];
#pragma unroll
  for (int i = 0; i < 4; i++)
#pragma unroll
    for (int j = 0; j < 2; j++)
      acc[i][j] = f32x4{0.f, 0.f, 0.f, 0.f};

  const int NIT = K >> 5;
  // short K: 2-barrier single-buffer, 24 KB LDS (6 blocks/CU)
  for (int it = 0; it < NIT; it++) {
    const int ko = it << 5;
    __syncthreads();
    gl2lds(pAh1 + ko, &AhL[wofs]); gl2lds(pAh2 + ko, &AhL[2048 + wofs]);
    gl2lds(pAl1 + ko, &AlL[wofs]); gl2lds(pAl2 + ko, &AlL[2048 + wofs]);
    gl2lds(pBh1 + ko, &BhL[wofs]); gl2lds(pBl1 + ko, &BlL[wofs]);
    __syncthreads();
    bf16x8 afh[4], afl[4], bqh[2], bql[2];
#pragma unroll
    for (int i = 0; i < 4; i++) {
      afh[i] = *(const bf16x8*)&AhL[(wm*64 + i*16 + l16) * 32 + (quad*8 ^ sxor)];
      afl[i] = *(const bf16x8*)&AlL[(wm*64 + i*16 + l16) * 32 + (quad*8 ^ sxor)];
    }
#pragma unroll
    for (int j = 0; j < 2; j++) {
      bqh[j] = *(const bf16x8*)&BhL[(wn*32 + j*16 + l16) * 32 + (quad*8 ^ sxor)];
      bql[j] = *(const bf16x8*)&BlL[(wn*32 + j*16 + l16) * 32 + (quad*8 ^ sxor)];
    }
#pragma unroll
    for (int i = 0; i < 4; i++)
#pragma unroll
      for (int j = 0; j < 2; j++) {
        acc[i][j] = __builtin_amdgcn_mfma_f32_16x16x32_bf16(afh[i], bqh[j], acc[i][j], 0, 0, 0);
        acc[i][j] = __builtin_amdgcn_mfma_f32_16x16x32_bf16(afh[i], bql[j], acc[i][j], 0, 0, 0);
        acc[i][j] = __builtin_amdgcn_mfma_f32_16x16x32_bf16(afl[i], bqh[j], acc[i][j], 0, 0, 0);
      }
  }

  if constexpr (MODE == 1) {
    // fused epilogue: kv_sum partials + V^T hi/lo store. Cols interleaved (2d|2d+1).
    const int b = m0 >> 11;              // all 128 rows in one batch (TT=2048)
    const int rb0 = m0 & (TT - 1);
    const int colbase = n0 + wn*32 + l16;
    float kvp[2] = {0.f, 0.f};
#pragma unroll
    for (int i = 0; i < 4; i++) {
#pragma unroll
      for (int j = 0; j < 2; j++) {
        const int col = colbase + j*16;
        const int d = col >> 1;
        float vals[4];
#pragma unroll
        for (int r = 0; r < 4; r++) {
          float vv = acc[i][j][r] + ((col & 1) ? bias1[d] : bias0[d]);
          float pa = __shfl_xor(vv, 1);          // partner parity (K<->V)
          if (!(col & 1)) kvp[j] += vv * pa;     // K*V on even lanes
          vals[r] = vv;
        }
        if (col & 1) {                           // odd lanes: store V^T hi/lo
          const int rr = rb0 + wm*64 + i*16 + quad*4;
          u16 hs[4], ls[4];
#pragma unroll
          for (int r = 0; r < 4; r++) {
            hs[r] = f2bf(vals[r]);
            ls[r] = f2bf(vals[r] - bf2f(hs[r]));
          }
          size_t o = (size_t)b * DD * TT + (size_t)d * TT + rr;
          *(uint2*)&outh[o] = uint2{(unsigned)hs[0] | ((unsigned)hs[1]<<16),
                                    (unsigned)hs[2] | ((unsigned)hs[3]<<16)};
          *(uint2*)&outl[o] = uint2{(unsigned)ls[0] | ((unsigned)ls[1]<<16),
                                    (unsigned)ls[2] | ((unsigned)ls[3]<<16)};
        }
      }
    }
#pragma unroll
    for (int j = 0; j < 2; j++) {               // reduce over quads, 1 atomic per d
      float p = kvp[j];
      p += __shfl_xor(p, 16);
      p += __shfl_xor(p, 32);
      const int col = colbase + j*16;
      if (!(col & 1) && quad == 0)
        atomicAdd(&out0[b * DD + (col >> 1)], p);
    }
  } else {
#pragma unroll
    for (int i = 0; i < 4; i++) {
#pragma unroll
      for (int r = 0; r < 4; r++) {
        const int row = m0 + wm*64 + i*16 + quad*4 + r;   // C/D: row = quad*4+reg
#pragma unroll
        for (int j = 0; j < 2; j++) {
          const int col = n0 + wn*32 + j*16 + l16;        // C/D: col = lane&15
          out0[(size_t)row * N + col] = acc[i][j][r] + bias0[col];
        }
      }
    }
  }
}

// ------------- fbV GEMM with FUSED fb split: wv = fb@V + kv_sum -------------
// A = fb f32 staged raw into LDS (same bytes as hi+lo pair); f32->(hi,lo) bf16
// conversion in-register via v_cvt_pk_bf16_f32 (RNE, matches split_f32_kernel).
// Eliminates the 256 MiB fb-split kernel entirely. 1D grid(512), per-batch XCD
// decode; dbuf DMA; 48 KB LDS (unchanged). A-side f32 swizzle: 8 chunks/row,
// phys = logical ^ (row&7), source-pre-swizzled (rule #21).
__global__ __launch_bounds__(256)
void fbv_kernel(const float* __restrict__ FB,
                const u16* __restrict__ Bhi, const u16* __restrict__ Blo,
                const float* __restrict__ kvs,
                u16* __restrict__ outh, u16* __restrict__ outl) {
  __shared__ float Af[2][128*32];               // 16 KB x2
  __shared__ u16 BhL[2][64*32], BlL[2][64*32];  // 4 KB x4
  const int gid = blockIdx.x;                // 0..511
  const int xcd = gid & 7, slot = gid >> 3;  // slot 0..63
  const int z  = xcd >> 1;                   // 2 XCDs per batch
  const int mt = (xcd & 1) + 2 * (slot >> 3);
  const int nt = slot & 7;                   // 8 n-tiles share A-tile, same XCD
  const int m0 = mt * 128, n0 = nt * 64;
  const float* A = FB + (size_t)z * TT * TT;
  const u16* Bh = Bhi + (size_t)z * DD * TT;
  const u16* Bl = Blo + (size_t)z * DD * TT;
  const int tid = threadIdx.x, lane = tid & 63, wave = tid >> 6;
  const int wm = wave >> 1, wn = wave & 1, quad = lane >> 4, l16 = lane & 15;
  const int sxor = ((l16 >> 1) & 3) << 3;    // B-side chunk XOR (u16 units)
  const int x7 = l16 & 7;                    // A-side f32 chunk XOR

  // A staging: 4 calls x 32 rows; thread covers (row = tid>>3, chunkpos = tid&7),
  // fetches global chunk (tid&7)^(row&7) so linear LDS holds the swizzled layout.
  const int arf = tid >> 3;                  // 0..31
  const int acf = (((tid & 7) ^ (arf & 7)) << 2);   // f32 units
  const float* pA = A + (size_t)(m0 + arf) * TT + acf;
  // B staging: legacy bf16 pattern
  const int ar1 = tid >> 2;
  const int ac1 = (((tid & 3) ^ ((tid >> 3) & 3)) << 3);
  const u16* pBh = Bh + (size_t)(n0 + ar1) * TT + ac1;
  const u16* pBl = Bl + (size_t)(n0 + ar1) * TT + ac1;
  const int wofs = wave * 512;               // u16 units (B dest)
  const int wofsA = wave << 8;               // f32 units (A dest, 1 KB/wave)

  f32x4 acc[4][2];
#pragma unroll
  for (int i = 0; i < 4; i++)
#pragma unroll
    for (int j = 0; j < 2; j++)
      acc[i][j] = f32x4{0.f, 0.f, 0.f, 0.f};

  const int NIT = TT >> 5;  // 64
#pragma unroll
  for (int c = 0; c < 4; c++)
    gl2lds_f(pA + (size_t)c * 32 * TT, &Af[0][c*1024 + wofsA]);
  gl2lds(pBh, &BhL[0][wofs]); gl2lds(pBl, &BlL[0][wofs]);
  for (int it = 0; it < NIT; it++) {
    const int buf = it & 1;
    __syncthreads();
    if (it + 1 < NIT) {
      const int ko = (it + 1) << 5;
#pragma unroll
      for (int c = 0; c < 4; c++)
        gl2lds_f(pA + (size_t)c * 32 * TT + ko, &Af[buf ^ 1][c*1024 + wofsA]);
      gl2lds(pBh + ko, &BhL[buf ^ 1][wofs]); gl2lds(pBl + ko, &BlL[buf ^ 1][wofs]);
    }
    bf16x8 afh[4], afl[4], bqh[2], bql[2];
#pragma unroll
    for (int i = 0; i < 4; i++) {
      const int rowR = wm*64 + i*16 + l16;
      f32x4 a0 = *(const f32x4*)&Af[buf][rowR*32 + ((((quad << 1)    ) ^ x7) << 2)];
      f32x4 a1 = *(const f32x4*)&Af[buf][rowR*32 + ((((quad << 1) | 1) ^ x7) << 2)];
      split2x4(a0, a1, &afh[i], &afl[i]);
    }
#pragma unroll
    for (int j = 0; j < 2; j++) {
      bqh[j] = *(const bf16x8*)&BhL[buf][(wn*32 + j*16 + l16) * 32 + (quad*8 ^ sxor)];
      bql[j] = *(const bf16x8*)&BlL[buf][(wn*32 + j*16 + l16) * 32 + (quad*8 ^ sxor)];
    }
#pragma unroll
    for (int i = 0; i < 4; i++)
#pragma unroll
      for (int j = 0; j < 2; j++) {
        acc[i][j] = __builtin_amdgcn_mfma_f32_16x16x32_bf16(afh[i], bqh[j], acc[i][j], 0, 0, 0);
        acc[i][j] = __builtin_amdgcn_mfma_f32_16x16x32_bf16(afh[i], bql[j], acc[i][j], 0, 0, 0);
        acc[i][j] = __builtin_amdgcn_mfma_f32_16x16x32_bf16(afl[i], bqh[j], acc[i][j], 0, 0, 0);
      }
  }

#pragma unroll
  for (int i = 0; i < 4; i++) {
#pragma unroll
    for (int r = 0; r < 4; r++) {
      const int row = m0 + wm*64 + i*16 + quad*4 + r;
#pragma unroll
      for (int j = 0; j < 2; j++) {
        const int col = n0 + wn*32 + j*16 + l16;
        float v = acc[i][j][r] + kvs[z * DD + col];
        u16 hv = f2bf(v);
        size_t idx = (size_t)z * TT * DD + (size_t)row * DD + col;
        outh[idx] = hv;
        outl[idx] = f2bf(v - bf2f(hv));
      }
    }
  }
}

// ------- z-fused sparse MoE GEMM1: h[base_e+m] = relu(gather(x1b)@W1_e + b1_e) -------
// grid(64, 16, NEXP); dbuf DMA (one barrier/iter), 32 KB LDS. XOR-swizzled LDS.
// (R5-verified 128-tile form; BM=256 regressed in R7.)
__global__ __launch_bounds__(256)
void moe_gemm1_kernel(const u16* __restrict__ X, const int* __restrict__ tokl,
                      const int* __restrict__ cnt, const u16* __restrict__ W1t,
                      const float* __restrict__ b1, u16* __restrict__ H) {
  const int e = blockIdx.z;
  int base = 0, cnte = 0;
#pragma unroll
  for (int i = 0; i < NEXP; i++) { int c = cnt[i]; if (i < e) base += c; if (i == e) cnte = c; }
  const int m0 = blockIdx.x * 128;
  if (m0 >= cnte) return;
  __shared__ u16 As[2][128*32], Bs[2][128*32];   // 16 + 16 KB
  const int n0 = blockIdx.y * 128;
  const int tid = threadIdx.x, lane = tid & 63, wave = tid >> 6;
  const int wm = wave >> 1, wn = wave & 1, quad = lane >> 4, l16 = lane & 15;
  const int sxor = ((l16 >> 1) & 3) << 3;
  const int ar1 = tid >> 2;
  const int ac1 = (((tid & 3) ^ ((tid >> 3) & 3)) << 3);
  const int i1 = m0 + ar1 < cnte ? m0 + ar1 : cnte - 1;
  const int i2 = m0 + ar1 + 64 < cnte ? m0 + ar1 + 64 : cnte - 1;
  const int t1 = tokl[e * NTOK + i1], t2 = tokl[e * NTOK + i2];
  const u16* Bt = W1t + (size_t)e * DD * FFF;
  const float* bias = b1 + (size_t)e * FFF;
  const u16* pA1 = X + (size_t)t1 * DD + ac1;
  const u16* pA2 = X + (size_t)t2 * DD + ac1;
  const u16* pB1 = Bt + (size_t)(n0 + ar1) * DD + ac1;
  const u16* pB2 = Bt + (size_t)(n0 + ar1 + 64) * DD + ac1;
  const int wofs = wave * 512;

  f32x4 acc[4][4];
#pragma unroll
  for (int i = 0; i < 4; i++)
#pragma unroll
    for (int j = 0; j < 4; j++)
      acc[i][j] = f32x4{0.f, 0.f, 0.f, 0.f};

  const int NIT = DD >> 5;  // 16
  gl2lds(pA1, &As[0][wofs]); gl2lds(pA2, &As[0][2048 + wofs]);
  gl2lds(pB1, &Bs[0][wofs]); gl2lds(pB2, &Bs[0][2048 + wofs]);
  for (int it = 0; it < NIT; it++) {
    const int buf = it & 1;
    __syncthreads();
    if (it + 1 < NIT) {
      const int ko = (it + 1) << 5;
      gl2lds(pA1 + ko, &As[buf ^ 1][wofs]); gl2lds(pA2 + ko, &As[buf ^ 1][2048 + wofs]);
      gl2lds(pB1 + ko, &Bs[buf ^ 1][wofs]); gl2lds(pB2 + ko, &Bs[buf ^ 1][2048 + wofs]);
    }
    bf16x8 af[4], bq[4];
#pragma unroll
    for (int i = 0; i < 4; i++)
      af[i] = *(const bf16x8*)&As[buf][(wm*64 + i*16 + l16)*32 + (quad*8 ^ sxor)];
#pragma unroll
    for (int j = 0; j < 4; j++)
      bq[j] = *(const bf16x8*)&Bs[buf][(wn*64 + j*16 + l16)*32 + (quad*8 ^ sxor)];
#pragma unroll
    for (int i = 0; i < 4; i++)
#pragma unroll
      for (int j = 0; j < 4; j++)
        acc[i][j] = __builtin_amdgcn_mfma_f32_16x16x32_bf16(af[i], bq[j], acc[i][j], 0, 0, 0);
  }

#pragma unroll
  for (int i = 0; i < 4; i++) {
#pragma unroll
    for (int r = 0; r < 4; r++) {
      const int m = m0 + wm*64 + i*16 + quad*4 + r;
      if (m < cnte) {
#pragma unroll
        for (int j = 0; j < 4; j++) {
          const int col = n0 + wn*64 + j*16 + l16;
          H[(size_t)(base + m) * FFF + col] = f2bf(fmaxf(acc[i][j][r] + bias[col], 0.f));
        }
      }
    }
  }
}

// ------- z-fused sparse MoE GEMM2, NO atomics: y[base_e+m] = w * (h@W2_e + b2_e), bf16 -------
// grid(64, 4, NEXP); BM=128, BN=128; dbuf DMA (K=2048); 32 KB LDS. (R5-verified form.)
__global__ __launch_bounds__(256)
void moe_gemm2_kernel(const u16* __restrict__ H, const int* __restrict__ tokl,
                      const int* __restrict__ cnt, const u16* __restrict__ W2t,
                      const float* __restrict__ b2, const float* __restrict__ wgt,
                      u16* __restrict__ Y) {
  const int e = blockIdx.z;
  int base = 0, cnte = 0;
#pragma unroll
  for (int i = 0; i < NEXP; i++) { int c = cnt[i]; if (i < e) base += c; if (i == e) cnte = c; }
  const int m0 = blockIdx.x * 128;
  if (m0 >= cnte) return;
  __shared__ u16 As[2][128*32], Bs[2][128*32];   // 16 + 16 KB
  const int n0 = blockIdx.y * 128;
  const int tid = threadIdx.x, lane = tid & 63, wave = tid >> 6;
  const int wm = wave >> 1, wn = wave & 1, quad = lane >> 4, l16 = lane & 15;
  const int sxor = ((l16 >> 1) & 3) << 3;
  const int ar1 = tid >> 2;
  const int ac1 = (((tid & 3) ^ ((tid >> 3) & 3)) << 3);
  const int i1 = m0 + ar1 < cnte ? m0 + ar1 : cnte - 1;
  const int i2 = m0 + ar1 + 64 < cnte ? m0 + ar1 + 64 : cnte - 1;
  const u16* Bt = W2t + (size_t)e * FFF * DD;
  const float* bias = b2 + (size_t)e * DD;
  const u16* pA1 = H + (size_t)(base + i1) * FFF + ac1;
  const u16* pA2 = H + (size_t)(base + i2) * FFF + ac1;
  const u16* pB1 = Bt + (size_t)(n0 + ar1) * FFF + ac1;
  const u16* pB2 = Bt + (size_t)(n0 + ar1 + 64) * FFF + ac1;
  const int wofs = wave * 512;

  f32x4 acc[4][4];
#pragma unroll
  for (int i = 0; i < 4; i++)
#pragma unroll
    for (int j = 0; j < 4; j++)
      acc[i][j] = f32x4{0.f, 0.f, 0.f, 0.f};

  const int NIT = FFF >> 5;  // 64
  gl2lds(pA1, &As[0][wofs]); gl2lds(pA2, &As[0][2048 + wofs]);
  gl2lds(pB1, &Bs[0][wofs]); gl2lds(pB2, &Bs[0][2048 + wofs]);
  for (int it = 0; it < NIT; it++) {
    const int buf = it & 1;
    __syncthreads();
    if (it + 1 < NIT) {
      const int ko = (it + 1) << 5;
      gl2lds(pA1 + ko, &As[buf ^ 1][wofs]); gl2lds(pA2 + ko, &As[buf ^ 1][2048 + wofs]);
      gl2lds(pB1 + ko, &Bs[buf ^ 1][wofs]); gl2lds(pB2 + ko, &Bs[buf ^ 1][2048 + wofs]);
    }
    bf16x8 af[4], bq[4];
#pragma unroll
    for (int i = 0; i < 4; i++)
      af[i] = *(const bf16x8*)&As[buf][(wm*64 + i*16 + l16)*32 + (quad*8 ^ sxor)];
#pragma unroll
    for (int j = 0; j < 4; j++)
      bq[j] = *(const bf16x8*)&Bs[buf][(wn*64 + j*16 + l16)*32 + (quad*8 ^ sxor)];
#pragma unroll
    for (int i = 0; i < 4; i++)
#pragma unroll
      for (int j = 0; j < 4; j++)
        acc[i][j] = __builtin_amdgcn_mfma_f32_16x16x32_bf16(af[i], bq[j], acc[i][j], 0, 0, 0);
  }

#pragma unroll
  for (int i = 0; i < 4; i++) {
#pragma unroll
    for (int r = 0; r < 4; r++) {
      const int m = m0 + wm*64 + i*16 + quad*4 + r;
      if (m < cnte) {
        const int t = tokl[e * NTOK + m];
        const float w = wgt[(size_t)t * NEXP + e];
#pragma unroll
        for (int j = 0; j < 4; j++) {
          const int col = n0 + wn*64 + j*16 + l16;
          Y[(size_t)(base + m) * DD + col] = f2bf((acc[i][j][r] + bias[col]) * w);
        }
      }
    }
  }
}

// ---------------- LN1: out = LN(a+b), f32 + bf16 ----------------
__global__ void ln_kernel(const float* __restrict__ a, const float* __restrict__ b,
                          const float* __restrict__ g, const float* __restrict__ beta,
                          float* __restrict__ outf, u16* __restrict__ outb) {
  int t = blockIdx.x;
  int tid = threadIdx.x;  // 256
  float v0 = a[(size_t)t*DD + tid]       + b[(size_t)t*DD + tid];
  float v1 = a[(size_t)t*DD + 256 + tid] + b[(size_t)t*DD + 256 + tid];
  float s = v0 + v1, s2 = v0*v0 + v1*v1;
  for (int off = 32; off; off >>= 1) { s += __shfl_down(s, off); s2 += __shfl_down(s2, off); }
  __shared__ float ws[4], ws2[4];
  if ((tid & 63) == 0) { ws[tid >> 6] = s; ws2[tid >> 6] = s2; }
  __syncthreads();
  if (tid == 0) {
    float ts = 0, ts2 = 0;
    for (int i = 0; i < 4; i++) { ts += ws[i]; ts2 += ws2[i]; }
    ws[0] = ts; ws2[0] = ts2;
  }
  __syncthreads();
  float mean = ws[0] * (1.f / DD);
  float var  = ws2[0] * (1.f / DD) - mean * mean;
  float rstd = rsqrtf(var + LNEPS);
  float o0 = (v0 - mean) * rstd * g[tid]       + beta[tid];
  float o1 = (v1 - mean) * rstd * g[256 + tid] + beta[256 + tid];
  outf[(size_t)t*DD + tid]       = o0;
  outf[(size_t)t*DD + 256 + tid] = o1;
  outb[(size_t)t*DD + tid]       = f2bf(o0);
  outb[(size_t)t*DD + 256 + tid] = f2bf(o1);
}

// ---- LN2 gather: out = LN(x1 + y[slot0] + y[slot1]) -- slots decode to h-rows ----
__global__ void ln2_kernel(const float* __restrict__ x1, const u16* __restrict__ Y,
                           const int* __restrict__ tokslot, const int* __restrict__ cnt,
                           const float* __restrict__ g, const float* __restrict__ beta,
                           float* __restrict__ out) {
  int t = blockIdx.x;
  int tid = threadIdx.x;  // 256
  const int c0 = cnt[0], c1 = cnt[1], c2 = cnt[2];
  const int s0 = tokslot[2*t], s1 = tokslot[2*t + 1];
  const int e0 = s0 >> 14, k0 = s0 & 16383;
  const int e1 = s1 >> 14, k1 = s1 & 16383;
  const int b0 = (e0 > 0 ? c0 : 0) + (e0 > 1 ? c1 : 0) + (e0 > 2 ? c2 : 0);
  const int b1 = (e1 > 0 ? c0 : 0) + (e1 > 1 ? c1 : 0) + (e1 > 2 ? c2 : 0);
  const u16* y0 = Y + (size_t)(b0 + k0) * DD;
  const u16* y1 = Y + (size_t)(b1 + k1) * DD;
  float v0 = x1[(size_t)t*DD + tid]       + bf2f(y0[tid])       + bf2f(y1[tid]);
  float v1 = x1[(size_t)t*DD + 256 + tid] + bf2f(y0[256 + tid]) + bf2f(y1[256 + tid]);
  float s = v0 + v1, s2 = v0*v0 + v1*v1;
  for (int off = 32; off; off >>= 1) { s += __shfl_down(s, off); s2 += __shfl_down(s2, off); }
  __shared__ float ws[4], ws2[4];
  if ((tid & 63) == 0) { ws[tid >> 6] = s; ws2[tid >> 6] = s2; }
  __syncthreads();
  if (tid == 0) {
    float ts = 0, ts2 = 0;
    for (int i = 0; i < 4; i++) { ts += ws[i]; ts2 += ws2[i]; }
    ws[0] = ts; ws2[0] = ts2;
  }
  __syncthreads();
  float mean = ws[0] * (1.f / DD);
  float var  = ws2[0] * (1.f / DD) - mean * mean;
  float rstd = rsqrtf(var + LNEPS);
  out[(size_t)t*DD + tid]       = (v0 - mean) * rstd * g[tid]       + beta[tid];
  out[(size_t)t*DD + 256 + tid] = (v1 - mean) * rstd * g[256 + tid] + beta[256 + tid];
}

// ------- gating with two-level routing + per-token slot records -------
__global__ __launch_bounds__(256)
void gate_kernel(const float* __restrict__ x1, const float* __restrict__ Wg,
                 const float* __restrict__ bg, float* __restrict__ wfull,
                 int* __restrict__ tokl, int* __restrict__ cnt, int* __restrict__ tokslot) {
  __shared__ int lcnt[NEXP];
  __shared__ int lbase[NEXP];
  __shared__ int lslots[NEXP][128];   // packed (t<<1)|which
  const int tid = threadIdx.x, lane = tid & 63, wave = tid >> 6;
  if (tid < NEXP) lcnt[tid] = 0;
  __syncthreads();
  const int tblk = blockIdx.x * 64;
  for (int i = 0; i < 16; i++) {
    const int t = tblk + wave * 16 + i;
    float s0 = 0.f, s1 = 0.f, s2 = 0.f, s3 = 0.f;
    for (int d = lane; d < DD; d += 64) {
      float xv = x1[(size_t)t * DD + d];
      float4 w = *(const float4*)&Wg[d * 4];
      s0 += xv * w.x; s1 += xv * w.y; s2 += xv * w.z; s3 += xv * w.w;
    }
    for (int off = 32; off; off >>= 1) {
      s0 += __shfl_down(s0, off); s1 += __shfl_down(s1, off);
      s2 += __shfl_down(s2, off); s3 += __shfl_down(s3, off);
    }
    if (lane == 0) {
      float sc[4] = {s0 + bg[0], s1 + bg[1], s2 + bg[2], s3 + bg[3]};
      float mx = fmaxf(fmaxf(sc[0], sc[1]), fmaxf(sc[2], sc[3]));
      float sum = 0.f;
      for (int e = 0; e < 4; e++) { sc[e] = expf(sc[e] - mx); sum += sc[e]; }
      float inv = 1.f / sum;
      for (int e = 0; e < 4; e++) sc[e] *= inv;
      int i0 = 0;
      for (int e = 1; e < 4; e++) if (sc[e] > sc[i0]) i0 = e;   // first-max tie rule == top_k
      int i1 = -1;
      for (int e = 0; e < 4; e++) { if (e == i0) continue; if (i1 < 0 || sc[e] > sc[i1]) i1 = e; }
      float w[4] = {0.f, 0.f, 0.f, 0.f};
      w[i0] = sc[i0]; w[i1] = sc[i1];
      *(float4*)&wfull[(size_t)t * 4] = float4{w[0], w[1], w[2], w[3]};
      int p0 = atomicAdd(&lcnt[i0], 1); lslots[i0][p0] = (t << 1);
      int p1 = atomicAdd(&lcnt[i1], 1); lslots[i1][p1] = (t << 1) | 1;
    }
  }
  __syncthreads();
  if (tid < NEXP) lbase[tid] = atomicAdd(&cnt[tid], lcnt[tid]);  // 4 global atomics/block
  __syncthreads();
  for (int idx = tid; idx < NEXP * 128; idx += 256) {
    const int e = idx >> 7, p = idx & 127;
    if (p < lcnt[e]) {
      const int v = lslots[e][p];
      const int t = v >> 1;
      const int pos = lbase[e] + p;
      tokl[e * NTOK + pos] = t;
      tokslot[2 * t + (v & 1)] = (e << 14) | pos;
    }
  }
}

extern "C" void kernel_launch(void* const* d_in, const int* in_sizes, int n_in,
                              void* d_out, int out_size, void* d_ws, size_t ws_size,
                              hipStream_t stream) {
  const float* x    = (const float*)d_in[0];
  const float* fb   = (const float*)d_in[1];
  const float* Wk   = (const float*)d_in[2];
  const float* bk   = (const float*)d_in[3];
  const float* Wv   = (const float*)d_in[4];
  const float* bv   = (const float*)d_in[5];
  const float* Wo   = (const float*)d_in[6];
  const float* bo   = (const float*)d_in[7];
  const float* ln1g = (const float*)d_in[8];
  const float* ln1b = (const float*)d_in[9];
  const float* Wg   = (const float*)d_in[10];
  const float* bg   = (const float*)d_in[11];
  const float* W1   = (const float*)d_in[12];
  const float* b1   = (const float*)d_in[13];
  const float* W2   = (const float*)d_in[14];
  const float* b2   = (const float*)d_in[15];
  const float* ln2g = (const float*)d_in[16];
  const float* ln2b = (const float*)d_in[17];

  // ---- workspace: lifetime-aliased regions (~132 MiB total) ----
  const size_t MiB = 1048576;
  char* ws = (char*)d_ws;
  // R1: 16 MiB.  xhi/xlo (step 2) -> wvhi/wvlo (4-5) -> x1b [0,8) (6-9)
  char* R1 = ws;
  u16* xhi  = (u16*)R1;             u16* xlo  = (u16*)(R1 + 8*MiB);
  u16* wvhi = (u16*)R1;             u16* wvlo = (u16*)(R1 + 8*MiB);
  u16* x1b  = (u16*)R1;
  // R2: 64 MiB.  h [0,64)  (fbhi/fblo eliminated -- fb split fused into fbv_kernel)
  char* R2 = ws + 16*MiB;
  u16* h    = (u16*)R2;
  // R3: 32 MiB.  vthi/vtlo [0,16) (2-4, written by fused KV gemm) -> attn (5-6) -> y bf16 (9-10);
  //              x1f [16,32) (6-10)
  char* R3 = ws + 80*MiB;
  u16* vthi   = (u16*)R3;           u16* vtlo  = (u16*)(R3 + 8*MiB);
  float* attn = (float*)R3;
  u16*  yb    = (u16*)R3;           // 16384 x 512 bf16 = 16 MiB
  float* x1f  = (float*)(R3 + 16*MiB);
  // R4: weights (whole lifetime) ~19 MiB
  char* R4 = ws + 112*MiB;
  u16* wkvthi = (u16*)R4;                         // 1 MiB  [1024][512] interleaved K|V
  u16* wkvtlo = (u16*)(R4 + 1*MiB);               // 1 MiB
  u16* wothi  = (u16*)(R4 + 2*MiB);               // 0.5 MiB [512][512]
  u16* wotlo  = (u16*)(R4 + 2*MiB + 512*1024);    // 0.5 MiB
  u16* w1t    = (u16*)(R4 + 3*MiB);               // 8 MiB  [E][FF][D]
  u16* w2t    = (u16*)(R4 + 11*MiB);              // 8 MiB  [E][D][FF]
  // R5: small (kvs and cnt contiguous -> single memset)
  char* R5 = ws + 131*MiB;
  float* kvs    = (float*)R5;                     // 8 KB
  int*   cnt    = (int*)(R5 + 8192);              // 16 B
  float* wfull  = (float*)(R5 + 16*1024);         // 128 KB
  int*   tokl   = (int*)(R5 + 160*1024);          // 128 KB
  int*   tokslot= (int*)(R5 + 320*1024);          // 128 KB
  (void)ws_size; (void)in_sizes; (void)n_in; (void)out_size;

  dim3 tb(32, 8);

  // 0) zero kv_sum + routing counters (one memset; re-poisoned every call)
  hipMemsetAsync(kvs, 0, 8192 + 16, stream);

  // 1) operand splits / weight transposes (fb split REMOVED -- fused into fbv_kernel)
  split_f32_kernel<<<NTOK * DD / 4 / 256, 256, 0, stream>>>(x, xhi, xlo, NTOK * DD / 4);
  transpose_split3_kernel<<<dim3(16, 16, 3), tb, 0, stream>>>(Wk, Wv, Wo,
                                                              wkvthi, wkvtlo, wothi, wotlo);
  transpose_cast_kernel<<<dim3(FFF/32, DD/32, NEXP), tb, 0, stream>>>(W1, w1t, DD, FFF);
  transpose_cast_kernel<<<dim3(DD/32, FFF/32, NEXP), tb, 0, stream>>>(W2, w2t, FFF, DD);

  // 2) fused KV: computes K,V projections; epilogue -> kv_sum atomics + V^T hi/lo.
  //    K is never written to memory. grid(64,16).
  gemm_split2_kernel<1><<<dim3(64, 16, 1), 256, 0, stream>>>(
      xhi, xlo, wkvthi, wkvtlo, bk, bv, kvs, vthi, vtlo,
      NTOK, 2*DD, DD, 0, 0, 0);

  // 3) wv[b] = fb[b]@V[b] + kv_sum[b]  (FUSED in-register fb split; per-batch XCD decode)
  fbv_kernel<<<dim3(512, 1, 1), 256, 0, stream>>>(fb, vthi, vtlo, kvs, wvhi, wvlo);

  // 4) attn = wv@Wo + bo  (split, f32 out; vt region dead -> attn lives there)
  gemm_split2_kernel<0><<<dim3(64, 8, 1), 256, 0, stream>>>(
      wvhi, wvlo, wothi, wotlo, bo, nullptr, attn, nullptr, nullptr,
      NTOK, DD, DD, 0, 0, 0);

  // 5) x1 = LN1(x + attn); x1b overwrites wv region (dead)
  ln_kernel<<<NTOK, 256, 0, stream>>>(x, attn, ln1g, ln1b, x1f, x1b);

  // 6) gate -> weights + per-expert token lists + per-token slot records
  gate_kernel<<<NTOK / 64, 256, 0, stream>>>(x1f, Wg, bg, wfull, tokl, cnt, tokslot);

  // 7) sparse top-2 MoE, z-fused, atomic-free: GEMM1 (dbuf) -> h, GEMM2 (dbuf) -> y
  moe_gemm1_kernel<<<dim3(NTOK/128, FFF/128, NEXP), 256, 0, stream>>>(
      x1b, tokl, cnt, w1t, b1, h);
  moe_gemm2_kernel<<<dim3(NTOK/128, DD/128, NEXP), 256, 0, stream>>>(
      h, tokl, cnt, w2t, b2, wfull, yb);

  // 8) out = LN2(x1 + y[slot0] + y[slot1])
  ln2_kernel<<<NTOK, 256, 0, stream>>>(x1f, yb, tokslot, cnt, ln2g, ln2b, (float*)d_out);
}

// Round 9
// 512.261 us; speedup vs baseline: 1.0289x; 1.0289x over previous
//
#include <hip/hip_runtime.h>
#include <stdint.h>

#define BB   4
#define TT   2048
#define DD   512
#define FFF  2048
#define NEXP 4
#define NTOK (BB*TT)
#define LNEPS 1e-5f

typedef unsigned short u16;
typedef __attribute__((ext_vector_type(8))) short bf16x8;  // 8 bf16 (4 VGPRs)
typedef __attribute__((ext_vector_type(4))) float f32x4;   // 4 f32 acc

__device__ __forceinline__ u16 f2bf(float f) {
  union { float f; unsigned u; } v; v.f = f;
  return (u16)((v.u + 0x7FFFu + ((v.u >> 16) & 1u)) >> 16);  // RNE
}
__device__ __forceinline__ float bf2f(u16 h) {
  union { unsigned u; float f; } v; v.u = (unsigned)h << 16; return v.f;
}

// async 16B/lane global->LDS DMA. LDS dest = wave-uniform base + lane*16.
__device__ __forceinline__ void gl2lds(const u16* g, u16* l) {
  __builtin_amdgcn_global_load_lds(
      (const __attribute__((address_space(1))) void*)g,
      (__attribute__((address_space(3))) void*)l, 16, 0, 0);
}

// ---- LDS bank-conflict fix (T2, rule #21), verified R5 (conflicts 4.26M -> 0):
// gl2lds writes linearly, so we pre-swizzle the GLOBAL source K-chunk per lane and
// XOR the same term on the ds_read side. Physical (row, c) holds logical
// (row, c ^ ((row>>1)&3)).
//   staging: ac1 = ((tid&3) ^ ((tid>>3)&3)) << 3
//   read:    chunk_off = quad*8 ^ (((l16>>1)&3)<<3)
// (R8 lesson: the f32-tile variant of this swizzle is NOT conflict-free; fb-split
//  fusion reverted.)

// ---------------- elementwise split f32 -> (hi, lo) bf16 ----------------
__global__ void split_f32_kernel(const float* __restrict__ in, u16* __restrict__ hi,
                                 u16* __restrict__ lo, int n4) {
  int i = blockIdx.x * blockDim.x + threadIdx.x;
  if (i >= n4) return;
  float4 f = ((const float4*)in)[i];
  u16 h0 = f2bf(f.x), h1 = f2bf(f.y), h2 = f2bf(f.z), h3 = f2bf(f.w);
  u16 l0 = f2bf(f.x - bf2f(h0)), l1 = f2bf(f.y - bf2f(h1));
  u16 l2 = f2bf(f.z - bf2f(h2)), l3 = f2bf(f.w - bf2f(h3));
  ((uint2*)hi)[i] = uint2{(unsigned)h0 | ((unsigned)h1 << 16), (unsigned)h2 | ((unsigned)h3 << 16)};
  ((uint2*)lo)[i] = uint2{(unsigned)l0 | ((unsigned)l1 << 16), (unsigned)l2 | ((unsigned)l3 << 16)};
}

// ------- fused 3x square transpose+split (Wk, Wv, Wo), z selects matrix -------
__global__ void transpose_split3_kernel(const float* __restrict__ s0, const float* __restrict__ s1,
                                        const float* __restrict__ s2,
                                        u16* __restrict__ kvhi, u16* __restrict__ kvlo,
                                        u16* __restrict__ ohi,  u16* __restrict__ olo) {
  __shared__ float tile[32][33];
  const int z = blockIdx.z;
  const float* in = (z == 0) ? s0 : (z == 1) ? s1 : s2;
  int c0 = blockIdx.x * 32, r0 = blockIdx.y * 32;
  int tx = threadIdx.x, ty = threadIdx.y;
#pragma unroll
  for (int k = 0; k < 4; k++)
    tile[ty + 8*k][tx] = in[(size_t)(r0 + ty + 8*k) * DD + c0 + tx];
  __syncthreads();
#pragma unroll
  for (int k = 0; k < 4; k++) {
    float v = tile[tx][ty + 8*k];
    u16 h = f2bf(v);
    u16 l = f2bf(v - bf2f(h));
    const int c = c0 + ty + 8*k;
    if (z < 2) {
      size_t idx = (size_t)(2*c + z) * DD + r0 + tx;
      kvhi[idx] = h; kvlo[idx] = l;
    } else {
      size_t idx = (size_t)c * DD + r0 + tx;
      ohi[idx] = h; olo[idx] = l;
    }
  }
}

// ------------- transpose + cast: f32 [Z][R][C] -> bf16 [Z][C][R] (MoE weights) -------------
__global__ void transpose_cast_kernel(const float* __restrict__ in, u16* __restrict__ out,
                                      int R, int C) {
  __shared__ float tile[32][33];
  int z = blockIdx.z;
  in  += (size_t)z * R * C;
  out += (size_t)z * R * C;
  int c0 = blockIdx.x * 32, r0 = blockIdx.y * 32;
  int tx = threadIdx.x, ty = threadIdx.y;
#pragma unroll
  for (int k = 0; k < 4; k++)
    tile[ty + 8*k][tx] = in[(size_t)(r0 + ty + 8*k) * C + c0 + tx];
  __syncthreads();
#pragma unroll
  for (int k = 0; k < 4; k++)
    out[(size_t)(c0 + ty + 8*k) * R + r0 + tx] = f2bf(tile[tx][ty + 8*k]);
}

// ---------------- split-bf16 GEMM (BM=128, BN=64), XCD-swizzled ----------------
// MODE 0: out0[row*N+col] = v + bias0[col]. grid(mt,nt), 2-barrier 1-buf (short K).
// MODE 1: fused KV: interleaved cols (2d=K_d, 2d+1=V_d). Epilogue computes
//         kv_sum atomics (out0=kvs) and writes V^T hi/lo (outh/outl, [B][D][T]).
// MODE 2: fbV: 1D grid(512), per-batch XCD decode; DOUBLE-BUFFERED DMA (long K).
template<int MODE>
__global__ __launch_bounds__(256)
void gemm_split2_kernel(const u16* __restrict__ Ahi, const u16* __restrict__ Alo,
                        const u16* __restrict__ Bhi, const u16* __restrict__ Blo,
                        const float* __restrict__ bias0, const float* __restrict__ bias1,
                        float* __restrict__ out0,
                        u16* __restrict__ outh, u16* __restrict__ outl,
                        int M, int N, int K,
                        long long sA, long long sB, long long sO) {
  constexpr int NBUF = (MODE == 2) ? 2 : 1;
  __shared__ u16 AhL[NBUF][128*32], AlL[NBUF][128*32];
  __shared__ u16 BhL[NBUF][64*32],  BlL[NBUF][64*32];

  int mt, nt, z;
  if constexpr (MODE == 2) {
    const int gid = blockIdx.x;                // 0..511
    const int xcd = gid & 7, slot = gid >> 3;  // slot 0..63
    z  = xcd >> 1;                             // 2 XCDs per batch
    mt = (xcd & 1) + 2 * (slot >> 3);          // 16 m-tiles/batch
    nt = slot & 7;                             // 8 n-tiles share A-tile, same XCD
  } else {
    mt = blockIdx.x; nt = blockIdx.y; z = blockIdx.z;
  }
  const int m0 = mt * 128, n0 = nt * 64;

  Ahi += (size_t)z * sA; Alo += (size_t)z * sA;
  Bhi += (size_t)z * sB; Blo += (size_t)z * sB;
  const int tid = threadIdx.x;
  const int lane = tid & 63, wave = tid >> 6;
  const int wm = wave >> 1, wn = wave & 1;
  const int quad = lane >> 4, l16 = lane & 15;
  const int sxor = ((l16 >> 1) & 3) << 3;      // read-side chunk XOR (u16 units)

  const int ar1 = tid >> 2;
  const int ac1 = (((tid & 3) ^ ((tid >> 3) & 3)) << 3);   // swizzled source chunk
  const u16* pAh1 = Ahi + (size_t)(m0 + ar1) * K + ac1;
  const u16* pAh2 = Ahi + (size_t)(m0 + ar1 + 64) * K + ac1;
  const u16* pAl1 = Alo + (size_t)(m0 + ar1) * K + ac1;
  const u16* pAl2 = Alo + (size_t)(m0 + ar1 + 64) * K + ac1;
  const u16* pBh1 = Bhi + (size_t)(n0 + ar1) * K + ac1;
  const u16* pBl1 = Blo + (size_t)(n0 + ar1) * K + ac1;
  const int wofs = wave * 512;

  f32x4 acc[4][2];
#pragma unroll
  for (int i = 0; i < 4; i++)
#pragma unroll
    for (int j = 0; j < 2; j++)
      acc[i][j] = f32x4{0.f, 0.f, 0.f, 0.f};

  const int NIT = K >> 5;
  if constexpr (MODE == 2) {
    // dbuf: one barrier per iter, prefetch overlaps MFMA
    gl2lds(pAh1, &AhL[0][wofs]); gl2lds(pAh2, &AhL[0][2048 + wofs]);
    gl2lds(pAl1, &AlL[0][wofs]); gl2lds(pAl2, &AlL[0][2048 + wofs]);
    gl2lds(pBh1, &BhL[0][wofs]); gl2lds(pBl1, &BlL[0][wofs]);
    for (int it = 0; it < NIT; it++) {
      const int buf = it & 1;
      __syncthreads();
      if (it + 1 < NIT) {
        const int ko = (it + 1) << 5;
        gl2lds(pAh1 + ko, &AhL[buf ^ 1][wofs]); gl2lds(pAh2 + ko, &AhL[buf ^ 1][2048 + wofs]);
        gl2lds(pAl1 + ko, &AlL[buf ^ 1][wofs]); gl2lds(pAl2 + ko, &AlL[buf ^ 1][2048 + wofs]);
        gl2lds(pBh1 + ko, &BhL[buf ^ 1][wofs]); gl2lds(pBl1 + ko, &BlL[buf ^ 1][wofs]);
      }
      bf16x8 afh[4], afl[4], bqh[2], bql[2];
#pragma unroll
      for (int i = 0; i < 4; i++) {
        afh[i] = *(const bf16x8*)&AhL[buf][(wm*64 + i*16 + l16) * 32 + (quad*8 ^ sxor)];
        afl[i] = *(const bf16x8*)&AlL[buf][(wm*64 + i*16 + l16) * 32 + (quad*8 ^ sxor)];
      }
#pragma unroll
      for (int j = 0; j < 2; j++) {
        bqh[j] = *(const bf16x8*)&BhL[buf][(wn*32 + j*16 + l16) * 32 + (quad*8 ^ sxor)];
        bql[j] = *(const bf16x8*)&BlL[buf][(wn*32 + j*16 + l16) * 32 + (quad*8 ^ sxor)];
      }
#pragma unroll
      for (int i = 0; i < 4; i++)
#pragma unroll
        for (int j = 0; j < 2; j++) {
          acc[i][j] = __builtin_amdgcn_mfma_f32_16x16x32_bf16(afh[i], bqh[j], acc[i][j], 0, 0, 0);
          acc[i][j] = __builtin_amdgcn_mfma_f32_16x16x32_bf16(afh[i], bql[j], acc[i][j], 0, 0, 0);
          acc[i][j] = __builtin_amdgcn_mfma_f32_16x16x32_bf16(afl[i], bqh[j], acc[i][j], 0, 0, 0);
        }
    }
  } else {
    // short K: 2-barrier single-buffer, 24 KB LDS (6 blocks/CU)
    for (int it = 0; it < NIT; it++) {
      const int ko = it << 5;
      __syncthreads();
      gl2lds(pAh1 + ko, &AhL[0][wofs]); gl2lds(pAh2 + ko, &AhL[0][2048 + wofs]);
      gl2lds(pAl1 + ko, &AlL[0][wofs]); gl2lds(pAl2 + ko, &AlL[0][2048 + wofs]);
      gl2lds(pBh1 + ko, &BhL[0][wofs]); gl2lds(pBl1 + ko, &BlL[0][wofs]);
      __syncthreads();
      bf16x8 afh[4], afl[4], bqh[2], bql[2];
#pragma unroll
      for (int i = 0; i < 4; i++) {
        afh[i] = *(const bf16x8*)&AhL[0][(wm*64 + i*16 + l16) * 32 + (quad*8 ^ sxor)];
        afl[i] = *(const bf16x8*)&AlL[0][(wm*64 + i*16 + l16) * 32 + (quad*8 ^ sxor)];
      }
#pragma unroll
      for (int j = 0; j < 2; j++) {
        bqh[j] = *(const bf16x8*)&BhL[0][(wn*32 + j*16 + l16) * 32 + (quad*8 ^ sxor)];
        bql[j] = *(const bf16x8*)&BlL[0][(wn*32 + j*16 + l16) * 32 + (quad*8 ^ sxor)];
      }
#pragma unroll
      for (int i = 0; i < 4; i++)
#pragma unroll
        for (int j = 0; j < 2; j++) {
          acc[i][j] = __builtin_amdgcn_mfma_f32_16x16x32_bf16(afh[i], bqh[j], acc[i][j], 0, 0, 0);
          acc[i][j] = __builtin_amdgcn_mfma_f32_16x16x32_bf16(afh[i], bql[j], acc[i][j], 0, 0, 0);
          acc[i][j] = __builtin_amdgcn_mfma_f32_16x16x32_bf16(afl[i], bqh[j], acc[i][j], 0, 0, 0);
        }
    }
  }

  if constexpr (MODE == 1) {
    // fused epilogue: kv_sum partials + V^T hi/lo store. Cols interleaved (2d|2d+1).
    const int b = m0 >> 11;              // all 128 rows in one batch (TT=2048)
    const int rb0 = m0 & (TT - 1);
    const int colbase = n0 + wn*32 + l16;
    float kvp[2] = {0.f, 0.f};
#pragma unroll
    for (int i = 0; i < 4; i++) {
#pragma unroll
      for (int j = 0; j < 2; j++) {
        const int col = colbase + j*16;
        const int d = col >> 1;
        float vals[4];
#pragma unroll
        for (int r = 0; r < 4; r++) {
          float vv = acc[i][j][r] + ((col & 1) ? bias1[d] : bias0[d]);
          float pa = __shfl_xor(vv, 1);          // partner parity (K<->V)
          if (!(col & 1)) kvp[j] += vv * pa;     // K*V on even lanes
          vals[r] = vv;
        }
        if (col & 1) {                           // odd lanes: store V^T hi/lo
          const int rr = rb0 + wm*64 + i*16 + quad*4;
          u16 hs[4], ls[4];
#pragma unroll
          for (int r = 0; r < 4; r++) {
            hs[r] = f2bf(vals[r]);
            ls[r] = f2bf(vals[r] - bf2f(hs[r]));
          }
          size_t o = (size_t)b * DD * TT + (size_t)d * TT + rr;
          *(uint2*)&outh[o] = uint2{(unsigned)hs[0] | ((unsigned)hs[1]<<16),
                                    (unsigned)hs[2] | ((unsigned)hs[3]<<16)};
          *(uint2*)&outl[o] = uint2{(unsigned)ls[0] | ((unsigned)ls[1]<<16),
                                    (unsigned)ls[2] | ((unsigned)ls[3]<<16)};
        }
      }
    }
#pragma unroll
    for (int j = 0; j < 2; j++) {               // reduce over quads, 1 atomic per d
      float p = kvp[j];
      p += __shfl_xor(p, 16);
      p += __shfl_xor(p, 32);
      const int col = colbase + j*16;
      if (!(col & 1) && quad == 0)
        atomicAdd(&out0[b * DD + (col >> 1)], p);
    }
  } else {
#pragma unroll
    for (int i = 0; i < 4; i++) {
#pragma unroll
      for (int r = 0; r < 4; r++) {
        const int row = m0 + wm*64 + i*16 + quad*4 + r;   // C/D: row = quad*4+reg
#pragma unroll
        for (int j = 0; j < 2; j++) {
          const int col = n0 + wn*32 + j*16 + l16;        // C/D: col = lane&15
          float v = acc[i][j][r];
          if constexpr (MODE == 0) {
            out0[(size_t)row * N + col] = v + bias0[col];
          } else {
            v += bias0[(size_t)z * DD + col];
            u16 hv = f2bf(v);
            size_t idx = (size_t)z * sO + (size_t)row * DD + col;
            outh[idx] = hv;
            outl[idx] = f2bf(v - bf2f(hv));
          }
        }
      }
    }
  }
}

// ------- z-fused sparse MoE GEMM1: h[base_e+m] = relu(gather(x1b)@W1_e + b1_e) -------
// grid(64, 16, NEXP); SINGLE-buffer 2-barrier (16 KB LDS -> up to 8 blocks/CU wave-cap).
// R8 theory: barrier-drain overlaps across co-resident blocks; dbuf's 32 KB capped
// residency. Staged bytes identical to dbuf. XOR-swizzled LDS (verified R5).
__global__ __launch_bounds__(256)
void moe_gemm1_kernel(const u16* __restrict__ X, const int* __restrict__ tokl,
                      const int* __restrict__ cnt, const u16* __restrict__ W1t,
                      const float* __restrict__ b1, u16* __restrict__ H) {
  const int e = blockIdx.z;
  int base = 0, cnte = 0;
#pragma unroll
  for (int i = 0; i < NEXP; i++) { int c = cnt[i]; if (i < e) base += c; if (i == e) cnte = c; }
  const int m0 = blockIdx.x * 128;
  if (m0 >= cnte) return;
  __shared__ u16 As[128*32], Bs[128*32];   // 8 + 8 KB
  const int n0 = blockIdx.y * 128;
  const int tid = threadIdx.x, lane = tid & 63, wave = tid >> 6;
  const int wm = wave >> 1, wn = wave & 1, quad = lane >> 4, l16 = lane & 15;
  const int sxor = ((l16 >> 1) & 3) << 3;
  const int ar1 = tid >> 2;
  const int ac1 = (((tid & 3) ^ ((tid >> 3) & 3)) << 3);
  const int i1 = m0 + ar1 < cnte ? m0 + ar1 : cnte - 1;
  const int i2 = m0 + ar1 + 64 < cnte ? m0 + ar1 + 64 : cnte - 1;
  const int t1 = tokl[e * NTOK + i1], t2 = tokl[e * NTOK + i2];
  const u16* Bt = W1t + (size_t)e * DD * FFF;
  const float* bias = b1 + (size_t)e * FFF;
  const u16* pA1 = X + (size_t)t1 * DD + ac1;
  const u16* pA2 = X + (size_t)t2 * DD + ac1;
  const u16* pB1 = Bt + (size_t)(n0 + ar1) * DD + ac1;
  const u16* pB2 = Bt + (size_t)(n0 + ar1 + 64) * DD + ac1;
  const int wofs = wave * 512;

  f32x4 acc[4][4];
#pragma unroll
  for (int i = 0; i < 4; i++)
#pragma unroll
    for (int j = 0; j < 4; j++)
      acc[i][j] = f32x4{0.f, 0.f, 0.f, 0.f};

  const int NIT = DD >> 5;  // 16
  for (int it = 0; it < NIT; it++) {
    const int ko = it << 5;
    __syncthreads();
    gl2lds(pA1 + ko, &As[wofs]); gl2lds(pA2 + ko, &As[2048 + wofs]);
    gl2lds(pB1 + ko, &Bs[wofs]); gl2lds(pB2 + ko, &Bs[2048 + wofs]);
    __syncthreads();
    bf16x8 af[4], bq[4];
#pragma unroll
    for (int i = 0; i < 4; i++)
      af[i] = *(const bf16x8*)&As[(wm*64 + i*16 + l16)*32 + (quad*8 ^ sxor)];
#pragma unroll
    for (int j = 0; j < 4; j++)
      bq[j] = *(const bf16x8*)&Bs[(wn*64 + j*16 + l16)*32 + (quad*8 ^ sxor)];
#pragma unroll
    for (int i = 0; i < 4; i++)
#pragma unroll
      for (int j = 0; j < 4; j++)
        acc[i][j] = __builtin_amdgcn_mfma_f32_16x16x32_bf16(af[i], bq[j], acc[i][j], 0, 0, 0);
  }

#pragma unroll
  for (int i = 0; i < 4; i++) {
#pragma unroll
    for (int r = 0; r < 4; r++) {
      const int m = m0 + wm*64 + i*16 + quad*4 + r;
      if (m < cnte) {
#pragma unroll
        for (int j = 0; j < 4; j++) {
          const int col = n0 + wn*64 + j*16 + l16;
          H[(size_t)(base + m) * FFF + col] = f2bf(fmaxf(acc[i][j][r] + bias[col], 0.f));
        }
      }
    }
  }
}

// ------- z-fused sparse MoE GEMM2, NO atomics: y[base_e+m] = w * (h@W2_e + b2_e), bf16 -------
// grid(64, 4, NEXP); BM=128, BN=128; dbuf DMA (K=2048); 32 KB LDS. (R5-verified form;
// grid supplies only ~2 blocks/CU so 1-buf residency gain doesn't apply here.)
__global__ __launch_bounds__(256)
void moe_gemm2_kernel(const u16* __restrict__ H, const int* __restrict__ tokl,
                      const int* __restrict__ cnt, const u16* __restrict__ W2t,
                      const float* __restrict__ b2, const float* __restrict__ wgt,
                      u16* __restrict__ Y) {
  const int e = blockIdx.z;
  int base = 0, cnte = 0;
#pragma unroll
  for (int i = 0; i < NEXP; i++) { int c = cnt[i]; if (i < e) base += c; if (i == e) cnte = c; }
  const int m0 = blockIdx.x * 128;
  if (m0 >= cnte) return;
  __shared__ u16 As[2][128*32], Bs[2][128*32];   // 16 + 16 KB
  const int n0 = blockIdx.y * 128;
  const int tid = threadIdx.x, lane = tid & 63, wave = tid >> 6;
  const int wm = wave >> 1, wn = wave & 1, quad = lane >> 4, l16 = lane & 15;
  const int sxor = ((l16 >> 1) & 3) << 3;
  const int ar1 = tid >> 2;
  const int ac1 = (((tid & 3) ^ ((tid >> 3) & 3)) << 3);
  const int i1 = m0 + ar1 < cnte ? m0 + ar1 : cnte - 1;
  const int i2 = m0 + ar1 + 64 < cnte ? m0 + ar1 + 64 : cnte - 1;
  const u16* Bt = W2t + (size_t)e * FFF * DD;
  const float* bias = b2 + (size_t)e * DD;
  const u16* pA1 = H + (size_t)(base + i1) * FFF + ac1;
  const u16* pA2 = H + (size_t)(base + i2) * FFF + ac1;
  const u16* pB1 = Bt + (size_t)(n0 + ar1) * FFF + ac1;
  const u16* pB2 = Bt + (size_t)(n0 + ar1 + 64) * FFF + ac1;
  const int wofs = wave * 512;

  f32x4 acc[4][4];
#pragma unroll
  for (int i = 0; i < 4; i++)
#pragma unroll
    for (int j = 0; j < 4; j++)
      acc[i][j] = f32x4{0.f, 0.f, 0.f, 0.f};

  const int NIT = FFF >> 5;  // 64
  gl2lds(pA1, &As[0][wofs]); gl2lds(pA2, &As[0][2048 + wofs]);
  gl2lds(pB1, &Bs[0][wofs]); gl2lds(pB2, &Bs[0][2048 + wofs]);
  for (int it = 0; it < NIT; it++) {
    const int buf = it & 1;
    __syncthreads();
    if (it + 1 < NIT) {
      const int ko = (it + 1) << 5;
      gl2lds(pA1 + ko, &As[buf ^ 1][wofs]); gl2lds(pA2 + ko, &As[buf ^ 1][2048 + wofs]);
      gl2lds(pB1 + ko, &Bs[buf ^ 1][wofs]); gl2lds(pB2 + ko, &Bs[buf ^ 1][2048 + wofs]);
    }
    bf16x8 af[4], bq[4];
#pragma unroll
    for (int i = 0; i < 4; i++)
      af[i] = *(const bf16x8*)&As[buf][(wm*64 + i*16 + l16)*32 + (quad*8 ^ sxor)];
#pragma unroll
    for (int j = 0; j < 4; j++)
      bq[j] = *(const bf16x8*)&Bs[buf][(wn*64 + j*16 + l16)*32 + (quad*8 ^ sxor)];
#pragma unroll
    for (int i = 0; i < 4; i++)
#pragma unroll
      for (int j = 0; j < 4; j++)
        acc[i][j] = __builtin_amdgcn_mfma_f32_16x16x32_bf16(af[i], bq[j], acc[i][j], 0, 0, 0);
  }

#pragma unroll
  for (int i = 0; i < 4; i++) {
#pragma unroll
    for (int r = 0; r < 4; r++) {
      const int m = m0 + wm*64 + i*16 + quad*4 + r;
      if (m < cnte) {
        const int t = tokl[e * NTOK + m];
        const float w = wgt[(size_t)t * NEXP + e];
#pragma unroll
        for (int j = 0; j < 4; j++) {
          const int col = n0 + wn*64 + j*16 + l16;
          Y[(size_t)(base + m) * DD + col] = f2bf((acc[i][j][r] + bias[col]) * w);
        }
      }
    }
  }
}

// ---------------- LN1: out = LN(a+b), f32 + bf16 ----------------
__global__ void ln_kernel(const float* __restrict__ a, const float* __restrict__ b,
                          const float* __restrict__ g, const float* __restrict__ beta,
                          float* __restrict__ outf, u16* __restrict__ outb) {
  int t = blockIdx.x;
  int tid = threadIdx.x;  // 256
  float v0 = a[(size_t)t*DD + tid]       + b[(size_t)t*DD + tid];
  float v1 = a[(size_t)t*DD + 256 + tid] + b[(size_t)t*DD + 256 + tid];
  float s = v0 + v1, s2 = v0*v0 + v1*v1;
  for (int off = 32; off; off >>= 1) { s += __shfl_down(s, off); s2 += __shfl_down(s2, off); }
  __shared__ float ws[4], ws2[4];
  if ((tid & 63) == 0) { ws[tid >> 6] = s; ws2[tid >> 6] = s2; }
  __syncthreads();
  if (tid == 0) {
    float ts = 0, ts2 = 0;
    for (int i = 0; i < 4; i++) { ts += ws[i]; ts2 += ws2[i]; }
    ws[0] = ts; ws2[0] = ts2;
  }
  __syncthreads();
  float mean = ws[0] * (1.f / DD);
  float var  = ws2[0] * (1.f / DD) - mean * mean;
  float rstd = rsqrtf(var + LNEPS);
  float o0 = (v0 - mean) * rstd * g[tid]       + beta[tid];
  float o1 = (v1 - mean) * rstd * g[256 + tid] + beta[256 + tid];
  outf[(size_t)t*DD + tid]       = o0;
  outf[(size_t)t*DD + 256 + tid] = o1;
  outb[(size_t)t*DD + tid]       = f2bf(o0);
  outb[(size_t)t*DD + 256 + tid] = f2bf(o1);
}

// ---- LN2 gather: out = LN(x1 + y[slot0] + y[slot1]) -- slots decode to h-rows ----
__global__ void ln2_kernel(const float* __restrict__ x1, const u16* __restrict__ Y,
                           const int* __restrict__ tokslot, const int* __restrict__ cnt,
                           const float* __restrict__ g, const float* __restrict__ beta,
                           float* __restrict__ out) {
  int t = blockIdx.x;
  int tid = threadIdx.x;  // 256
  const int c0 = cnt[0], c1 = cnt[1], c2 = cnt[2];
  const int s0 = tokslot[2*t], s1 = tokslot[2*t + 1];
  const int e0 = s0 >> 14, k0 = s0 & 16383;
  const int e1 = s1 >> 14, k1 = s1 & 16383;
  const int b0 = (e0 > 0 ? c0 : 0) + (e0 > 1 ? c1 : 0) + (e0 > 2 ? c2 : 0);
  const int b1 = (e1 > 0 ? c0 : 0) + (e1 > 1 ? c1 : 0) + (e1 > 2 ? c2 : 0);
  const u16* y0 = Y + (size_t)(b0 + k0) * DD;
  const u16* y1 = Y + (size_t)(b1 + k1) * DD;
  float v0 = x1[(size_t)t*DD + tid]       + bf2f(y0[tid])       + bf2f(y1[tid]);
  float v1 = x1[(size_t)t*DD + 256 + tid] + bf2f(y0[256 + tid]) + bf2f(y1[256 + tid]);
  float s = v0 + v1, s2 = v0*v0 + v1*v1;
  for (int off = 32; off; off >>= 1) { s += __shfl_down(s, off); s2 += __shfl_down(s2, off); }
  __shared__ float ws[4], ws2[4];
  if ((tid & 63) == 0) { ws[tid >> 6] = s; ws2[tid >> 6] = s2; }
  __syncthreads();
  if (tid == 0) {
    float ts = 0, ts2 = 0;
    for (int i = 0; i < 4; i++) { ts += ws[i]; ts2 += ws2[i]; }
    ws[0] = ts; ws2[0] = ts2;
  }
  __syncthreads();
  float mean = ws[0] * (1.f / DD);
  float var  = ws2[0] * (1.f / DD) - mean * mean;
  float rstd = rsqrtf(var + LNEPS);
  out[(size_t)t*DD + tid]       = (v0 - mean) * rstd * g[tid]       + beta[tid];
  out[(size_t)t*DD + 256 + tid] = (v1 - mean) * rstd * g[256 + tid] + beta[256 + tid];
}

// ------- gating with two-level routing + per-token slot records -------
__global__ __launch_bounds__(256)
void gate_kernel(const float* __restrict__ x1, const float* __restrict__ Wg,
                 const float* __restrict__ bg, float* __restrict__ wfull,
                 int* __restrict__ tokl, int* __restrict__ cnt, int* __restrict__ tokslot) {
  __shared__ int lcnt[NEXP];
  __shared__ int lbase[NEXP];
  __shared__ int lslots[NEXP][128];   // packed (t<<1)|which
  const int tid = threadIdx.x, lane = tid & 63, wave = tid >> 6;
  if (tid < NEXP) lcnt[tid] = 0;
  __syncthreads();
  const int tblk = blockIdx.x * 64;
  for (int i = 0; i < 16; i++) {
    const int t = tblk + wave * 16 + i;
    float s0 = 0.f, s1 = 0.f, s2 = 0.f, s3 = 0.f;
    for (int d = lane; d < DD; d += 64) {
      float xv = x1[(size_t)t * DD + d];
      float4 w = *(const float4*)&Wg[d * 4];
      s0 += xv * w.x; s1 += xv * w.y; s2 += xv * w.z; s3 += xv * w.w;
    }
    for (int off = 32; off; off >>= 1) {
      s0 += __shfl_down(s0, off); s1 += __shfl_down(s1, off);
      s2 += __shfl_down(s2, off); s3 += __shfl_down(s3, off);
    }
    if (lane == 0) {
      float sc[4] = {s0 + bg[0], s1 + bg[1], s2 + bg[2], s3 + bg[3]};
      float mx = fmaxf(fmaxf(sc[0], sc[1]), fmaxf(sc[2], sc[3]));
      float sum = 0.f;
      for (int e = 0; e < 4; e++) { sc[e] = expf(sc[e] - mx); sum += sc[e]; }
      float inv = 1.f / sum;
      for (int e = 0; e < 4; e++) sc[e] *= inv;
      int i0 = 0;
      for (int e = 1; e < 4; e++) if (sc[e] > sc[i0]) i0 = e;   // first-max tie rule == top_k
      int i1 = -1;
      for (int e = 0; e < 4; e++) { if (e == i0) continue; if (i1 < 0 || sc[e] > sc[i1]) i1 = e; }
      float w[4] = {0.f, 0.f, 0.f, 0.f};
      w[i0] = sc[i0]; w[i1] = sc[i1];
      *(float4*)&wfull[(size_t)t * 4] = float4{w[0], w[1], w[2], w[3]};
      int p0 = atomicAdd(&lcnt[i0], 1); lslots[i0][p0] = (t << 1);
      int p1 = atomicAdd(&lcnt[i1], 1); lslots[i1][p1] = (t << 1) | 1;
    }
  }
  __syncthreads();
  if (tid < NEXP) lbase[tid] = atomicAdd(&cnt[tid], lcnt[tid]);  // 4 global atomics/block
  __syncthreads();
  for (int idx = tid; idx < NEXP * 128; idx += 256) {
    const int e = idx >> 7, p = idx & 127;
    if (p < lcnt[e]) {
      const int v = lslots[e][p];
      const int t = v >> 1;
      const int pos = lbase[e] + p;
      tokl[e * NTOK + pos] = t;
      tokslot[2 * t + (v & 1)] = (e << 14) | pos;
    }
  }
}

extern "C" void kernel_launch(void* const* d_in, const int* in_sizes, int n_in,
                              void* d_out, int out_size, void* d_ws, size_t ws_size,
                              hipStream_t stream) {
  const float* x    = (const float*)d_in[0];
  const float* fb   = (const float*)d_in[1];
  const float* Wk   = (const float*)d_in[2];
  const float* bk   = (const float*)d_in[3];
  const float* Wv   = (const float*)d_in[4];
  const float* bv   = (const float*)d_in[5];
  const float* Wo   = (const float*)d_in[6];
  const float* bo   = (const float*)d_in[7];
  const float* ln1g = (const float*)d_in[8];
  const float* ln1b = (const float*)d_in[9];
  const float* Wg   = (const float*)d_in[10];
  const float* bg   = (const float*)d_in[11];
  const float* W1   = (const float*)d_in[12];
  const float* b1   = (const float*)d_in[13];
  const float* W2   = (const float*)d_in[14];
  const float* b2   = (const float*)d_in[15];
  const float* ln2g = (const float*)d_in[16];
  const float* ln2b = (const float*)d_in[17];

  // ---- workspace: lifetime-aliased regions (~132 MiB total) ----
  const size_t MiB = 1048576;
  char* ws = (char*)d_ws;
  // R1: 16 MiB.  xhi/xlo (step 2) -> wvhi/wvlo (4-5) -> x1b [0,8) (6-9)
  char* R1 = ws;
  u16* xhi  = (u16*)R1;             u16* xlo  = (u16*)(R1 + 8*MiB);
  u16* wvhi = (u16*)R1;             u16* wvlo = (u16*)(R1 + 8*MiB);
  u16* x1b  = (u16*)R1;
  // R2: 64 MiB.  fbhi/fblo (1-4) -> h [0,64)
  char* R2 = ws + 16*MiB;
  u16* fbhi = (u16*)R2;             u16* fblo = (u16*)(R2 + 32*MiB);
  u16* h    = (u16*)R2;
  // R3: 32 MiB.  vthi/vtlo [0,16) (2-4, written by fused KV gemm) -> attn (5-6) -> y bf16 (9-10);
  //              x1f [16,32) (6-10)
  char* R3 = ws + 80*MiB;
  u16* vthi   = (u16*)R3;           u16* vtlo  = (u16*)(R3 + 8*MiB);
  float* attn = (float*)R3;
  u16*  yb    = (u16*)R3;           // 16384 x 512 bf16 = 16 MiB
  float* x1f  = (float*)(R3 + 16*MiB);
  // R4: weights (whole lifetime) ~19 MiB
  char* R4 = ws + 112*MiB;
  u16* wkvthi = (u16*)R4;                         // 1 MiB  [1024][512] interleaved K|V
  u16* wkvtlo = (u16*)(R4 + 1*MiB);               // 1 MiB
  u16* wothi  = (u16*)(R4 + 2*MiB);               // 0.5 MiB [512][512]
  u16* wotlo  = (u16*)(R4 + 2*MiB + 512*1024);    // 0.5 MiB
  u16* w1t    = (u16*)(R4 + 3*MiB);               // 8 MiB  [E][FF][D]
  u16* w2t    = (u16*)(R4 + 11*MiB);              // 8 MiB  [E][D][FF]
  // R5: small (kvs and cnt contiguous -> single memset)
  char* R5 = ws + 131*MiB;
  float* kvs    = (float*)R5;                     // 8 KB
  int*   cnt    = (int*)(R5 + 8192);              // 16 B
  float* wfull  = (float*)(R5 + 16*1024);         // 128 KB
  int*   tokl   = (int*)(R5 + 160*1024);          // 128 KB
  int*   tokslot= (int*)(R5 + 320*1024);          // 128 KB
  (void)ws_size; (void)in_sizes; (void)n_in; (void)out_size;

  dim3 tb(32, 8);

  // 0) zero kv_sum + routing counters (one memset; re-poisoned every call)
  hipMemsetAsync(kvs, 0, 8192 + 16, stream);

  // 1) operand splits / weight transposes (Wk|Wv interleaved for fused KV epilogue)
  split_f32_kernel<<<NTOK * DD / 4 / 256, 256, 0, stream>>>(x, xhi, xlo, NTOK * DD / 4);
  split_f32_kernel<<<BB * TT * TT / 4 / 256, 256, 0, stream>>>(fb, fbhi, fblo, BB * TT * TT / 4);
  transpose_split3_kernel<<<dim3(16, 16, 3), tb, 0, stream>>>(Wk, Wv, Wo,
                                                              wkvthi, wkvtlo, wothi, wotlo);
  transpose_cast_kernel<<<dim3(FFF/32, DD/32, NEXP), tb, 0, stream>>>(W1, w1t, DD, FFF);
  transpose_cast_kernel<<<dim3(DD/32, FFF/32, NEXP), tb, 0, stream>>>(W2, w2t, FFF, DD);

  // 2) fused KV: computes K,V projections; epilogue -> kv_sum atomics + V^T hi/lo.
  //    K is never written to memory. grid(64,16).
  gemm_split2_kernel<1><<<dim3(64, 16, 1), 256, 0, stream>>>(
      xhi, xlo, wkvthi, wkvtlo, bk, bv, kvs, vthi, vtlo,
      NTOK, 2*DD, DD, 0, 0, 0);

  // 3) wv[b] = fb[b]@V[b] + kv_sum[b]  (split, dbuf, hi/lo epilogue; per-batch XCD decode)
  gemm_split2_kernel<2><<<dim3(512, 1, 1), 256, 0, stream>>>(
      fbhi, fblo, vthi, vtlo, kvs, nullptr, nullptr, wvhi, wvlo,
      TT, DD, TT, (long long)TT*TT, (long long)DD*TT, (long long)TT*DD);

  // 4) attn = wv@Wo + bo  (split, f32 out; vt region dead -> attn lives there)
  gemm_split2_kernel<0><<<dim3(64, 8, 1), 256, 0, stream>>>(
      wvhi, wvlo, wothi, wotlo, bo, nullptr, attn, nullptr, nullptr,
      NTOK, DD, DD, 0, 0, 0);

  // 5) x1 = LN1(x + attn); x1b overwrites wv region (dead)
  ln_kernel<<<NTOK, 256, 0, stream>>>(x, attn, ln1g, ln1b, x1f, x1b);

  // 6) gate -> weights + per-expert token lists + per-token slot records
  gate_kernel<<<NTOK / 64, 256, 0, stream>>>(x1f, Wg, bg, wfull, tokl, cnt, tokslot);

  // 7) sparse top-2 MoE, z-fused, atomic-free: GEMM1 (1-buf, 16 KB) -> h, GEMM2 (dbuf) -> y
  moe_gemm1_kernel<<<dim3(NTOK/128, FFF/128, NEXP), 256, 0, stream>>>(
      x1b, tokl, cnt, w1t, b1, h);
  moe_gemm2_kernel<<<dim3(NTOK/128, DD/128, NEXP), 256, 0, stream>>>(
      h, tokl, cnt, w2t, b2, wfull, yb);

  // 8) out = LN2(x1 + y[slot0] + y[slot1])
  ln2_kernel<<<NTOK, 256, 0, stream>>>(x1f, yb, tokslot, cnt, ln2g, ln2b, (float*)d_out);
}

// Round 10
// 508.148 us; speedup vs baseline: 1.0373x; 1.0081x over previous
//
#include <hip/hip_runtime.h>
#include <stdint.h>

#define BB   4
#define TT   2048
#define DD   512
#define FFF  2048
#define NEXP 4
#define NTOK (BB*TT)
#define LNEPS 1e-5f

typedef unsigned short u16;
typedef __attribute__((ext_vector_type(8))) short bf16x8;  // 8 bf16 (4 VGPRs)
typedef __attribute__((ext_vector_type(4))) float f32x4;   // 4 f32 acc

__device__ __forceinline__ u16 f2bf(float f) {
  union { float f; unsigned u; } v; v.f = f;
  return (u16)((v.u + 0x7FFFu + ((v.u >> 16) & 1u)) >> 16);  // RNE
}
__device__ __forceinline__ float bf2f(u16 h) {
  union { unsigned u; float f; } v; v.u = (unsigned)h << 16; return v.f;
}

// async 16B/lane global->LDS DMA. LDS dest = wave-uniform base + lane*16.
__device__ __forceinline__ void gl2lds(const u16* g, u16* l) {
  __builtin_amdgcn_global_load_lds(
      (const __attribute__((address_space(1))) void*)g,
      (__attribute__((address_space(3))) void*)l, 16, 0, 0);
}

// ---- LDS bank-conflict fix (T2, rule #21), verified R5 (conflicts 4.26M -> 0):
// gl2lds writes linearly, so we pre-swizzle the GLOBAL source K-chunk per lane and
// XOR the same term on the ds_read side. Physical (row, c) holds logical
// (row, c ^ ((row>>1)&3)).
//   staging: ac1 = ((tid&3) ^ ((tid>>3)&3)) << 3
//   read:    chunk_off = quad*8 ^ (((l16>>1)&3)<<3)

// ---------------- elementwise split f32 -> (hi, lo) bf16 ----------------
__global__ void split_f32_kernel(const float* __restrict__ in, u16* __restrict__ hi,
                                 u16* __restrict__ lo, int n4) {
  int i = blockIdx.x * blockDim.x + threadIdx.x;
  if (i >= n4) return;
  float4 f = ((const float4*)in)[i];
  u16 h0 = f2bf(f.x), h1 = f2bf(f.y), h2 = f2bf(f.z), h3 = f2bf(f.w);
  u16 l0 = f2bf(f.x - bf2f(h0)), l1 = f2bf(f.y - bf2f(h1));
  u16 l2 = f2bf(f.z - bf2f(h2)), l3 = f2bf(f.w - bf2f(h3));
  ((uint2*)hi)[i] = uint2{(unsigned)h0 | ((unsigned)h1 << 16), (unsigned)h2 | ((unsigned)h3 << 16)};
  ((uint2*)lo)[i] = uint2{(unsigned)l0 | ((unsigned)l1 << 16), (unsigned)l2 | ((unsigned)l3 << 16)};
}

// ------- fused 3x square transpose+split (Wk, Wv, Wo), z selects matrix -------
__global__ void transpose_split3_kernel(const float* __restrict__ s0, const float* __restrict__ s1,
                                        const float* __restrict__ s2,
                                        u16* __restrict__ kvhi, u16* __restrict__ kvlo,
                                        u16* __restrict__ ohi,  u16* __restrict__ olo) {
  __shared__ float tile[32][33];
  const int z = blockIdx.z;
  const float* in = (z == 0) ? s0 : (z == 1) ? s1 : s2;
  int c0 = blockIdx.x * 32, r0 = blockIdx.y * 32;
  int tx = threadIdx.x, ty = threadIdx.y;
#pragma unroll
  for (int k = 0; k < 4; k++)
    tile[ty + 8*k][tx] = in[(size_t)(r0 + ty + 8*k) * DD + c0 + tx];
  __syncthreads();
#pragma unroll
  for (int k = 0; k < 4; k++) {
    float v = tile[tx][ty + 8*k];
    u16 h = f2bf(v);
    u16 l = f2bf(v - bf2f(h));
    const int c = c0 + ty + 8*k;
    if (z < 2) {
      size_t idx = (size_t)(2*c + z) * DD + r0 + tx;
      kvhi[idx] = h; kvlo[idx] = l;
    } else {
      size_t idx = (size_t)c * DD + r0 + tx;
      ohi[idx] = h; olo[idx] = l;
    }
  }
}

// ------------- transpose + cast: f32 [Z][R][C] -> bf16 [Z][C][R] (MoE weights) -------------
__global__ void transpose_cast_kernel(const float* __restrict__ in, u16* __restrict__ out,
                                      int R, int C) {
  __shared__ float tile[32][33];
  int z = blockIdx.z;
  in  += (size_t)z * R * C;
  out += (size_t)z * R * C;
  int c0 = blockIdx.x * 32, r0 = blockIdx.y * 32;
  int tx = threadIdx.x, ty = threadIdx.y;
#pragma unroll
  for (int k = 0; k < 4; k++)
    tile[ty + 8*k][tx] = in[(size_t)(r0 + ty + 8*k) * C + c0 + tx];
  __syncthreads();
#pragma unroll
  for (int k = 0; k < 4; k++)
    out[(size_t)(c0 + ty + 8*k) * R + r0 + tx] = f2bf(tile[tx][ty + 8*k]);
}

// ---------------- split-bf16 GEMM (BM=128, BN=64), XCD-swizzled ----------------
// MODE 0: out0[row*N+col] = v + bias0[col]. grid(mt,nt), 2-barrier 1-buf (short K).
// MODE 1: fused KV: interleaved cols (2d=K_d, 2d+1=V_d). Epilogue computes
//         kv_sum atomics (out0=kvs) and writes V^T hi/lo (outh/outl, [B][D][T]).
// MODE 2: fbV: 1D grid(512), per-batch XCD decode; DOUBLE-BUFFERED DMA (long K).
template<int MODE>
__global__ __launch_bounds__(256)
void gemm_split2_kernel(const u16* __restrict__ Ahi, const u16* __restrict__ Alo,
                        const u16* __restrict__ Bhi, const u16* __restrict__ Blo,
                        const float* __restrict__ bias0, const float* __restrict__ bias1,
                        float* __restrict__ out0,
                        u16* __restrict__ outh, u16* __restrict__ outl,
                        int M, int N, int K,
                        long long sA, long long sB, long long sO) {
  constexpr int NBUF = (MODE == 2) ? 2 : 1;
  __shared__ u16 AhL[NBUF][128*32], AlL[NBUF][128*32];
  __shared__ u16 BhL[NBUF][64*32],  BlL[NBUF][64*32];

  int mt, nt, z;
  if constexpr (MODE == 2) {
    const int gid = blockIdx.x;                // 0..511
    const int xcd = gid & 7, slot = gid >> 3;  // slot 0..63
    z  = xcd >> 1;                             // 2 XCDs per batch
    mt = (xcd & 1) + 2 * (slot >> 3);          // 16 m-tiles/batch
    nt = slot & 7;                             // 8 n-tiles share A-tile, same XCD
  } else {
    mt = blockIdx.x; nt = blockIdx.y; z = blockIdx.z;
  }
  const int m0 = mt * 128, n0 = nt * 64;

  Ahi += (size_t)z * sA; Alo += (size_t)z * sA;
  Bhi += (size_t)z * sB; Blo += (size_t)z * sB;
  const int tid = threadIdx.x;
  const int lane = tid & 63, wave = tid >> 6;
  const int wm = wave >> 1, wn = wave & 1;
  const int quad = lane >> 4, l16 = lane & 15;
  const int sxor = ((l16 >> 1) & 3) << 3;      // read-side chunk XOR (u16 units)

  const int ar1 = tid >> 2;
  const int ac1 = (((tid & 3) ^ ((tid >> 3) & 3)) << 3);   // swizzled source chunk
  const u16* pAh1 = Ahi + (size_t)(m0 + ar1) * K + ac1;
  const u16* pAh2 = Ahi + (size_t)(m0 + ar1 + 64) * K + ac1;
  const u16* pAl1 = Alo + (size_t)(m0 + ar1) * K + ac1;
  const u16* pAl2 = Alo + (size_t)(m0 + ar1 + 64) * K + ac1;
  const u16* pBh1 = Bhi + (size_t)(n0 + ar1) * K + ac1;
  const u16* pBl1 = Blo + (size_t)(n0 + ar1) * K + ac1;
  const int wofs = wave * 512;

  f32x4 acc[4][2];
#pragma unroll
  for (int i = 0; i < 4; i++)
#pragma unroll
    for (int j = 0; j < 2; j++)
      acc[i][j] = f32x4{0.f, 0.f, 0.f, 0.f};

  const int NIT = K >> 5;
  if constexpr (MODE == 2) {
    // dbuf: one barrier per iter, prefetch overlaps MFMA
    gl2lds(pAh1, &AhL[0][wofs]); gl2lds(pAh2, &AhL[0][2048 + wofs]);
    gl2lds(pAl1, &AlL[0][wofs]); gl2lds(pAl2, &AlL[0][2048 + wofs]);
    gl2lds(pBh1, &BhL[0][wofs]); gl2lds(pBl1, &BlL[0][wofs]);
    for (int it = 0; it < NIT; it++) {
      const int buf = it & 1;
      __syncthreads();
      if (it + 1 < NIT) {
        const int ko = (it + 1) << 5;
        gl2lds(pAh1 + ko, &AhL[buf ^ 1][wofs]); gl2lds(pAh2 + ko, &AhL[buf ^ 1][2048 + wofs]);
        gl2lds(pAl1 + ko, &AlL[buf ^ 1][wofs]); gl2lds(pAl2 + ko, &AlL[buf ^ 1][2048 + wofs]);
        gl2lds(pBh1 + ko, &BhL[buf ^ 1][wofs]); gl2lds(pBl1 + ko, &BlL[buf ^ 1][wofs]);
      }
      bf16x8 afh[4], afl[4], bqh[2], bql[2];
#pragma unroll
      for (int i = 0; i < 4; i++) {
        afh[i] = *(const bf16x8*)&AhL[buf][(wm*64 + i*16 + l16) * 32 + (quad*8 ^ sxor)];
        afl[i] = *(const bf16x8*)&AlL[buf][(wm*64 + i*16 + l16) * 32 + (quad*8 ^ sxor)];
      }
#pragma unroll
      for (int j = 0; j < 2; j++) {
        bqh[j] = *(const bf16x8*)&BhL[buf][(wn*32 + j*16 + l16) * 32 + (quad*8 ^ sxor)];
        bql[j] = *(const bf16x8*)&BlL[buf][(wn*32 + j*16 + l16) * 32 + (quad*8 ^ sxor)];
      }
#pragma unroll
      for (int i = 0; i < 4; i++)
#pragma unroll
        for (int j = 0; j < 2; j++) {
          acc[i][j] = __builtin_amdgcn_mfma_f32_16x16x32_bf16(afh[i], bqh[j], acc[i][j], 0, 0, 0);
          acc[i][j] = __builtin_amdgcn_mfma_f32_16x16x32_bf16(afh[i], bql[j], acc[i][j], 0, 0, 0);
          acc[i][j] = __builtin_amdgcn_mfma_f32_16x16x32_bf16(afl[i], bqh[j], acc[i][j], 0, 0, 0);
        }
    }
  } else {
    // short K: 2-barrier single-buffer, 24 KB LDS (6 blocks/CU)
    for (int it = 0; it < NIT; it++) {
      const int ko = it << 5;
      __syncthreads();
      gl2lds(pAh1 + ko, &AhL[0][wofs]); gl2lds(pAh2 + ko, &AhL[0][2048 + wofs]);
      gl2lds(pAl1 + ko, &AlL[0][wofs]); gl2lds(pAl2 + ko, &AlL[0][2048 + wofs]);
      gl2lds(pBh1 + ko, &BhL[0][wofs]); gl2lds(pBl1 + ko, &BlL[0][wofs]);
      __syncthreads();
      bf16x8 afh[4], afl[4], bqh[2], bql[2];
#pragma unroll
      for (int i = 0; i < 4; i++) {
        afh[i] = *(const bf16x8*)&AhL[0][(wm*64 + i*16 + l16) * 32 + (quad*8 ^ sxor)];
        afl[i] = *(const bf16x8*)&AlL[0][(wm*64 + i*16 + l16) * 32 + (quad*8 ^ sxor)];
      }
#pragma unroll
      for (int j = 0; j < 2; j++) {
        bqh[j] = *(const bf16x8*)&BhL[0][(wn*32 + j*16 + l16) * 32 + (quad*8 ^ sxor)];
        bql[j] = *(const bf16x8*)&BlL[0][(wn*32 + j*16 + l16) * 32 + (quad*8 ^ sxor)];
      }
#pragma unroll
      for (int i = 0; i < 4; i++)
#pragma unroll
        for (int j = 0; j < 2; j++) {
          acc[i][j] = __builtin_amdgcn_mfma_f32_16x16x32_bf16(afh[i], bqh[j], acc[i][j], 0, 0, 0);
          acc[i][j] = __builtin_amdgcn_mfma_f32_16x16x32_bf16(afh[i], bql[j], acc[i][j], 0, 0, 0);
          acc[i][j] = __builtin_amdgcn_mfma_f32_16x16x32_bf16(afl[i], bqh[j], acc[i][j], 0, 0, 0);
        }
    }
  }

  if constexpr (MODE == 1) {
    // fused epilogue: kv_sum partials + V^T hi/lo store. Cols interleaved (2d|2d+1).
    const int b = m0 >> 11;              // all 128 rows in one batch (TT=2048)
    const int rb0 = m0 & (TT - 1);
    const int colbase = n0 + wn*32 + l16;
    float kvp[2] = {0.f, 0.f};
#pragma unroll
    for (int i = 0; i < 4; i++) {
#pragma unroll
      for (int j = 0; j < 2; j++) {
        const int col = colbase + j*16;
        const int d = col >> 1;
        float vals[4];
#pragma unroll
        for (int r = 0; r < 4; r++) {
          float vv = acc[i][j][r] + ((col & 1) ? bias1[d] : bias0[d]);
          float pa = __shfl_xor(vv, 1);          // partner parity (K<->V)
          if (!(col & 1)) kvp[j] += vv * pa;     // K*V on even lanes
          vals[r] = vv;
        }
        if (col & 1) {                           // odd lanes: store V^T hi/lo
          const int rr = rb0 + wm*64 + i*16 + quad*4;
          u16 hs[4], ls[4];
#pragma unroll
          for (int r = 0; r < 4; r++) {
            hs[r] = f2bf(vals[r]);
            ls[r] = f2bf(vals[r] - bf2f(hs[r]));
          }
          size_t o = (size_t)b * DD * TT + (size_t)d * TT + rr;
          *(uint2*)&outh[o] = uint2{(unsigned)hs[0] | ((unsigned)hs[1]<<16),
                                    (unsigned)hs[2] | ((unsigned)hs[3]<<16)};
          *(uint2*)&outl[o] = uint2{(unsigned)ls[0] | ((unsigned)ls[1]<<16),
                                    (unsigned)ls[2] | ((unsigned)ls[3]<<16)};
        }
      }
    }
#pragma unroll
    for (int j = 0; j < 2; j++) {               // reduce over quads, 1 atomic per d
      float p = kvp[j];
      p += __shfl_xor(p, 16);
      p += __shfl_xor(p, 32);
      const int col = colbase + j*16;
      if (!(col & 1) && quad == 0)
        atomicAdd(&out0[b * DD + (col >> 1)], p);
    }
  } else {
#pragma unroll
    for (int i = 0; i < 4; i++) {
#pragma unroll
      for (int r = 0; r < 4; r++) {
        const int row = m0 + wm*64 + i*16 + quad*4 + r;   // C/D: row = quad*4+reg
#pragma unroll
        for (int j = 0; j < 2; j++) {
          const int col = n0 + wn*32 + j*16 + l16;        // C/D: col = lane&15
          float v = acc[i][j][r];
          if constexpr (MODE == 0) {
            out0[(size_t)row * N + col] = v + bias0[col];
          } else {
            v += bias0[(size_t)z * DD + col];
            u16 hv = f2bf(v);
            size_t idx = (size_t)z * sO + (size_t)row * DD + col;
            outh[idx] = hv;
            outl[idx] = f2bf(v - bf2f(hv));
          }
        }
      }
    }
  }
}

// ------- z-fused sparse MoE GEMM1: h[base_e+m] = relu(gather(x1b)@W1_e + b1_e) -------
// grid(64, 16, NEXP); SINGLE-buffer 2-barrier (16 KB LDS). R9: 75.4 us (control kernel).
__global__ __launch_bounds__(256)
void moe_gemm1_kernel(const u16* __restrict__ X, const int* __restrict__ tokl,
                      const int* __restrict__ cnt, const u16* __restrict__ W1t,
                      const float* __restrict__ b1, u16* __restrict__ H) {
  const int e = blockIdx.z;
  int base = 0, cnte = 0;
#pragma unroll
  for (int i = 0; i < NEXP; i++) { int c = cnt[i]; if (i < e) base += c; if (i == e) cnte = c; }
  const int m0 = blockIdx.x * 128;
  if (m0 >= cnte) return;
  __shared__ u16 As[128*32], Bs[128*32];   // 8 + 8 KB
  const int n0 = blockIdx.y * 128;
  const int tid = threadIdx.x, lane = tid & 63, wave = tid >> 6;
  const int wm = wave >> 1, wn = wave & 1, quad = lane >> 4, l16 = lane & 15;
  const int sxor = ((l16 >> 1) & 3) << 3;
  const int ar1 = tid >> 2;
  const int ac1 = (((tid & 3) ^ ((tid >> 3) & 3)) << 3);
  const int i1 = m0 + ar1 < cnte ? m0 + ar1 : cnte - 1;
  const int i2 = m0 + ar1 + 64 < cnte ? m0 + ar1 + 64 : cnte - 1;
  const int t1 = tokl[e * NTOK + i1], t2 = tokl[e * NTOK + i2];
  const u16* Bt = W1t + (size_t)e * DD * FFF;
  const float* bias = b1 + (size_t)e * FFF;
  const u16* pA1 = X + (size_t)t1 * DD + ac1;
  const u16* pA2 = X + (size_t)t2 * DD + ac1;
  const u16* pB1 = Bt + (size_t)(n0 + ar1) * DD + ac1;
  const u16* pB2 = Bt + (size_t)(n0 + ar1 + 64) * DD + ac1;
  const int wofs = wave * 512;

  f32x4 acc[4][4];
#pragma unroll
  for (int i = 0; i < 4; i++)
#pragma unroll
    for (int j = 0; j < 4; j++)
      acc[i][j] = f32x4{0.f, 0.f, 0.f, 0.f};

  const int NIT = DD >> 5;  // 16
  for (int it = 0; it < NIT; it++) {
    const int ko = it << 5;
    __syncthreads();
    gl2lds(pA1 + ko, &As[wofs]); gl2lds(pA2 + ko, &As[2048 + wofs]);
    gl2lds(pB1 + ko, &Bs[wofs]); gl2lds(pB2 + ko, &Bs[2048 + wofs]);
    __syncthreads();
    bf16x8 af[4], bq[4];
#pragma unroll
    for (int i = 0; i < 4; i++)
      af[i] = *(const bf16x8*)&As[(wm*64 + i*16 + l16)*32 + (quad*8 ^ sxor)];
#pragma unroll
    for (int j = 0; j < 4; j++)
      bq[j] = *(const bf16x8*)&Bs[(wn*64 + j*16 + l16)*32 + (quad*8 ^ sxor)];
#pragma unroll
    for (int i = 0; i < 4; i++)
#pragma unroll
      for (int j = 0; j < 4; j++)
        acc[i][j] = __builtin_amdgcn_mfma_f32_16x16x32_bf16(af[i], bq[j], acc[i][j], 0, 0, 0);
  }

#pragma unroll
  for (int i = 0; i < 4; i++) {
#pragma unroll
    for (int r = 0; r < 4; r++) {
      const int m = m0 + wm*64 + i*16 + quad*4 + r;
      if (m < cnte) {
#pragma unroll
        for (int j = 0; j < 4; j++) {
          const int col = n0 + wn*64 + j*16 + l16;
          H[(size_t)(base + m) * FFF + col] = f2bf(fmaxf(acc[i][j][r] + bias[col], 0.f));
        }
      }
    }
  }
}

// ------- z-fused sparse MoE GEMM2, NO atomics: y[base_e+m] = w * (h@W2_e + b2_e), bf16 -------
// grid(64, 4, NEXP); BM=128, BN=128; K=2048 (64 iters).
// R10: depth-2 counted-vmcnt pipeline, NBUF=3 (48 KB -> 3 blocks/CU >= grid's 2).
// Raw s_barrier + vmcnt(4) steady (never 0 mid-loop): loads get ~2 iters (~500 cyc)
// to land vs dbuf's ~1. Safety: buf written at it (for it+2) was last read at it-1;
// all waves' it-1 ds_reads are consumed (compiler lgkm waits before MFMA) before
// they reach barrier(it). One sched_barrier(0) stops ds_read hoisting (rule #18).
__global__ __launch_bounds__(256)
void moe_gemm2_kernel(const u16* __restrict__ H, const int* __restrict__ tokl,
                      const int* __restrict__ cnt, const u16* __restrict__ W2t,
                      const float* __restrict__ b2, const float* __restrict__ wgt,
                      u16* __restrict__ Y) {
  const int e = blockIdx.z;
  int base = 0, cnte = 0;
#pragma unroll
  for (int i = 0; i < NEXP; i++) { int c = cnt[i]; if (i < e) base += c; if (i == e) cnte = c; }
  const int m0 = blockIdx.x * 128;
  if (m0 >= cnte) return;
  __shared__ u16 As[3][128*32], Bs[3][128*32];   // 24 + 24 KB
  const int n0 = blockIdx.y * 128;
  const int tid = threadIdx.x, lane = tid & 63, wave = tid >> 6;
  const int wm = wave >> 1, wn = wave & 1, quad = lane >> 4, l16 = lane & 15;
  const int sxor = ((l16 >> 1) & 3) << 3;
  const int ar1 = tid >> 2;
  const int ac1 = (((tid & 3) ^ ((tid >> 3) & 3)) << 3);
  const int i1 = m0 + ar1 < cnte ? m0 + ar1 : cnte - 1;
  const int i2 = m0 + ar1 + 64 < cnte ? m0 + ar1 + 64 : cnte - 1;
  const u16* Bt = W2t + (size_t)e * FFF * DD;
  const float* bias = b2 + (size_t)e * DD;
  const u16* pA1 = H + (size_t)(base + i1) * FFF + ac1;
  const u16* pA2 = H + (size_t)(base + i2) * FFF + ac1;
  const u16* pB1 = Bt + (size_t)(n0 + ar1) * FFF + ac1;
  const u16* pB2 = Bt + (size_t)(n0 + ar1 + 64) * FFF + ac1;
  const int wofs = wave * 512;

  f32x4 acc[4][4];
#pragma unroll
  for (int i = 0; i < 4; i++)
#pragma unroll
    for (int j = 0; j < 4; j++)
      acc[i][j] = f32x4{0.f, 0.f, 0.f, 0.f};

  const int NIT = FFF >> 5;  // 64
  // prologue: issue tiles 0 and 1 (8 loads/thread in flight)
  gl2lds(pA1, &As[0][wofs]); gl2lds(pA2, &As[0][2048 + wofs]);
  gl2lds(pB1, &Bs[0][wofs]); gl2lds(pB2, &Bs[0][2048 + wofs]);
  gl2lds(pA1 + 32, &As[1][wofs]); gl2lds(pA2 + 32, &As[1][2048 + wofs]);
  gl2lds(pB1 + 32, &Bs[1][wofs]); gl2lds(pB2 + 32, &Bs[1][2048 + wofs]);
#pragma unroll 1
  for (int it = 0; it < NIT; it++) {
    const int buf = it % 3;
    if (it < NIT - 1) {
      asm volatile("s_waitcnt vmcnt(4)" ::: "memory");   // own tile done; next stays in flight
    } else {
      asm volatile("s_waitcnt vmcnt(0)" ::: "memory");   // last tile: drain
    }
    __builtin_amdgcn_s_barrier();
    __builtin_amdgcn_sched_barrier(0);
    if (it + 2 < NIT) {
      const int ko = (it + 2) << 5;
      const int pb = (it + 2) % 3;
      gl2lds(pA1 + ko, &As[pb][wofs]); gl2lds(pA2 + ko, &As[pb][2048 + wofs]);
      gl2lds(pB1 + ko, &Bs[pb][wofs]); gl2lds(pB2 + ko, &Bs[pb][2048 + wofs]);
    }
    bf16x8 af[4], bq[4];
#pragma unroll
    for (int i = 0; i < 4; i++)
      af[i] = *(const bf16x8*)&As[buf][(wm*64 + i*16 + l16)*32 + (quad*8 ^ sxor)];
#pragma unroll
    for (int j = 0; j < 4; j++)
      bq[j] = *(const bf16x8*)&Bs[buf][(wn*64 + j*16 + l16)*32 + (quad*8 ^ sxor)];
#pragma unroll
    for (int i = 0; i < 4; i++)
#pragma unroll
      for (int j = 0; j < 4; j++)
        acc[i][j] = __builtin_amdgcn_mfma_f32_16x16x32_bf16(af[i], bq[j], acc[i][j], 0, 0, 0);
  }

#pragma unroll
  for (int i = 0; i < 4; i++) {
#pragma unroll
    for (int r = 0; r < 4; r++) {
      const int m = m0 + wm*64 + i*16 + quad*4 + r;
      if (m < cnte) {
        const int t = tokl[e * NTOK + m];
        const float w = wgt[(size_t)t * NEXP + e];
#pragma unroll
        for (int j = 0; j < 4; j++) {
          const int col = n0 + wn*64 + j*16 + l16;
          Y[(size_t)(base + m) * DD + col] = f2bf((acc[i][j][r] + bias[col]) * w);
        }
      }
    }
  }
}

// ---------------- LN1: out = LN(a+b), f32 + bf16 ----------------
__global__ void ln_kernel(const float* __restrict__ a, const float* __restrict__ b,
                          const float* __restrict__ g, const float* __restrict__ beta,
                          float* __restrict__ outf, u16* __restrict__ outb) {
  int t = blockIdx.x;
  int tid = threadIdx.x;  // 256
  float v0 = a[(size_t)t*DD + tid]       + b[(size_t)t*DD + tid];
  float v1 = a[(size_t)t*DD + 256 + tid] + b[(size_t)t*DD + 256 + tid];
  float s = v0 + v1, s2 = v0*v0 + v1*v1;
  for (int off = 32; off; off >>= 1) { s += __shfl_down(s, off); s2 += __shfl_down(s2, off); }
  __shared__ float ws[4], ws2[4];
  if ((tid & 63) == 0) { ws[tid >> 6] = s; ws2[tid >> 6] = s2; }
  __syncthreads();
  if (tid == 0) {
    float ts = 0, ts2 = 0;
    for (int i = 0; i < 4; i++) { ts += ws[i]; ts2 += ws2[i]; }
    ws[0] = ts; ws2[0] = ts2;
  }
  __syncthreads();
  float mean = ws[0] * (1.f / DD);
  float var  = ws2[0] * (1.f / DD) - mean * mean;
  float rstd = rsqrtf(var + LNEPS);
  float o0 = (v0 - mean) * rstd * g[tid]       + beta[tid];
  float o1 = (v1 - mean) * rstd * g[256 + tid] + beta[256 + tid];
  outf[(size_t)t*DD + tid]       = o0;
  outf[(size_t)t*DD + 256 + tid] = o1;
  outb[(size_t)t*DD + tid]       = f2bf(o0);
  outb[(size_t)t*DD + 256 + tid] = f2bf(o1);
}

// ---- LN2 gather: out = LN(x1 + y[slot0] + y[slot1]) -- slots decode to h-rows ----
__global__ void ln2_kernel(const float* __restrict__ x1, const u16* __restrict__ Y,
                           const int* __restrict__ tokslot, const int* __restrict__ cnt,
                           const float* __restrict__ g, const float* __restrict__ beta,
                           float* __restrict__ out) {
  int t = blockIdx.x;
  int tid = threadIdx.x;  // 256
  const int c0 = cnt[0], c1 = cnt[1], c2 = cnt[2];
  const int s0 = tokslot[2*t], s1 = tokslot[2*t + 1];
  const int e0 = s0 >> 14, k0 = s0 & 16383;
  const int e1 = s1 >> 14, k1 = s1 & 16383;
  const int b0 = (e0 > 0 ? c0 : 0) + (e0 > 1 ? c1 : 0) + (e0 > 2 ? c2 : 0);
  const int b1 = (e1 > 0 ? c0 : 0) + (e1 > 1 ? c1 : 0) + (e1 > 2 ? c2 : 0);
  const u16* y0 = Y + (size_t)(b0 + k0) * DD;
  const u16* y1 = Y + (size_t)(b1 + k1) * DD;
  float v0 = x1[(size_t)t*DD + tid]       + bf2f(y0[tid])       + bf2f(y1[tid]);
  float v1 = x1[(size_t)t*DD + 256 + tid] + bf2f(y0[256 + tid]) + bf2f(y1[256 + tid]);
  float s = v0 + v1, s2 = v0*v0 + v1*v1;
  for (int off = 32; off; off >>= 1) { s += __shfl_down(s, off); s2 += __shfl_down(s2, off); }
  __shared__ float ws[4], ws2[4];
  if ((tid & 63) == 0) { ws[tid >> 6] = s; ws2[tid >> 6] = s2; }
  __syncthreads();
  if (tid == 0) {
    float ts = 0, ts2 = 0;
    for (int i = 0; i < 4; i++) { ts += ws[i]; ts2 += ws2[i]; }
    ws[0] = ts; ws2[0] = ts2;
  }
  __syncthreads();
  float mean = ws[0] * (1.f / DD);
  float var  = ws2[0] * (1.f / DD) - mean * mean;
  float rstd = rsqrtf(var + LNEPS);
  out[(size_t)t*DD + tid]       = (v0 - mean) * rstd * g[tid]       + beta[tid];
  out[(size_t)t*DD + 256 + tid] = (v1 - mean) * rstd * g[256 + tid] + beta[256 + tid];
}

// ------- gating with two-level routing + per-token slot records -------
__global__ __launch_bounds__(256)
void gate_kernel(const float* __restrict__ x1, const float* __restrict__ Wg,
                 const float* __restrict__ bg, float* __restrict__ wfull,
                 int* __restrict__ tokl, int* __restrict__ cnt, int* __restrict__ tokslot) {
  __shared__ int lcnt[NEXP];
  __shared__ int lbase[NEXP];
  __shared__ int lslots[NEXP][128];   // packed (t<<1)|which
  const int tid = threadIdx.x, lane = tid & 63, wave = tid >> 6;
  if (tid < NEXP) lcnt[tid] = 0;
  __syncthreads();
  const int tblk = blockIdx.x * 64;
  for (int i = 0; i < 16; i++) {
    const int t = tblk + wave * 16 + i;
    float s0 = 0.f, s1 = 0.f, s2 = 0.f, s3 = 0.f;
    for (int d = lane; d < DD; d += 64) {
      float xv = x1[(size_t)t * DD + d];
      float4 w = *(const float4*)&Wg[d * 4];
      s0 += xv * w.x; s1 += xv * w.y; s2 += xv * w.z; s3 += xv * w.w;
    }
    for (int off = 32; off; off >>= 1) {
      s0 += __shfl_down(s0, off); s1 += __shfl_down(s1, off);
      s2 += __shfl_down(s2, off); s3 += __shfl_down(s3, off);
    }
    if (lane == 0) {
      float sc[4] = {s0 + bg[0], s1 + bg[1], s2 + bg[2], s3 + bg[3]};
      float mx = fmaxf(fmaxf(sc[0], sc[1]), fmaxf(sc[2], sc[3]));
      float sum = 0.f;
      for (int e = 0; e < 4; e++) { sc[e] = expf(sc[e] - mx); sum += sc[e]; }
      float inv = 1.f / sum;
      for (int e = 0; e < 4; e++) sc[e] *= inv;
      int i0 = 0;
      for (int e = 1; e < 4; e++) if (sc[e] > sc[i0]) i0 = e;   // first-max tie rule == top_k
      int i1 = -1;
      for (int e = 0; e < 4; e++) { if (e == i0) continue; if (i1 < 0 || sc[e] > sc[i1]) i1 = e; }
      float w[4] = {0.f, 0.f, 0.f, 0.f};
      w[i0] = sc[i0]; w[i1] = sc[i1];
      *(float4*)&wfull[(size_t)t * 4] = float4{w[0], w[1], w[2], w[3]};
      int p0 = atomicAdd(&lcnt[i0], 1); lslots[i0][p0] = (t << 1);
      int p1 = atomicAdd(&lcnt[i1], 1); lslots[i1][p1] = (t << 1) | 1;
    }
  }
  __syncthreads();
  if (tid < NEXP) lbase[tid] = atomicAdd(&cnt[tid], lcnt[tid]);  // 4 global atomics/block
  __syncthreads();
  for (int idx = tid; idx < NEXP * 128; idx += 256) {
    const int e = idx >> 7, p = idx & 127;
    if (p < lcnt[e]) {
      const int v = lslots[e][p];
      const int t = v >> 1;
      const int pos = lbase[e] + p;
      tokl[e * NTOK + pos] = t;
      tokslot[2 * t + (v & 1)] = (e << 14) | pos;
    }
  }
}

extern "C" void kernel_launch(void* const* d_in, const int* in_sizes, int n_in,
                              void* d_out, int out_size, void* d_ws, size_t ws_size,
                              hipStream_t stream) {
  const float* x    = (const float*)d_in[0];
  const float* fb   = (const float*)d_in[1];
  const float* Wk   = (const float*)d_in[2];
  const float* bk   = (const float*)d_in[3];
  const float* Wv   = (const float*)d_in[4];
  const float* bv   = (const float*)d_in[5];
  const float* Wo   = (const float*)d_in[6];
  const float* bo   = (const float*)d_in[7];
  const float* ln1g = (const float*)d_in[8];
  const float* ln1b = (const float*)d_in[9];
  const float* Wg   = (const float*)d_in[10];
  const float* bg   = (const float*)d_in[11];
  const float* W1   = (const float*)d_in[12];
  const float* b1   = (const float*)d_in[13];
  const float* W2   = (const float*)d_in[14];
  const float* b2   = (const float*)d_in[15];
  const float* ln2g = (const float*)d_in[16];
  const float* ln2b = (const float*)d_in[17];

  // ---- workspace: lifetime-aliased regions (~132 MiB total) ----
  const size_t MiB = 1048576;
  char* ws = (char*)d_ws;
  // R1: 16 MiB.  xhi/xlo (step 2) -> wvhi/wvlo (4-5) -> x1b [0,8) (6-9)
  char* R1 = ws;
  u16* xhi  = (u16*)R1;             u16* xlo  = (u16*)(R1 + 8*MiB);
  u16* wvhi = (u16*)R1;             u16* wvlo = (u16*)(R1 + 8*MiB);
  u16* x1b  = (u16*)R1;
  // R2: 64 MiB.  fbhi/fblo (1-4) -> h [0,64)
  char* R2 = ws + 16*MiB;
  u16* fbhi = (u16*)R2;             u16* fblo = (u16*)(R2 + 32*MiB);
  u16* h    = (u16*)R2;
  // R3: 32 MiB.  vthi/vtlo [0,16) (2-4, written by fused KV gemm) -> attn (5-6) -> y bf16 (9-10);
  //              x1f [16,32) (6-10)
  char* R3 = ws + 80*MiB;
  u16* vthi   = (u16*)R3;           u16* vtlo  = (u16*)(R3 + 8*MiB);
  float* attn = (float*)R3;
  u16*  yb    = (u16*)R3;           // 16384 x 512 bf16 = 16 MiB
  float* x1f  = (float*)(R3 + 16*MiB);
  // R4: weights (whole lifetime) ~19 MiB
  char* R4 = ws + 112*MiB;
  u16* wkvthi = (u16*)R4;                         // 1 MiB  [1024][512] interleaved K|V
  u16* wkvtlo = (u16*)(R4 + 1*MiB);               // 1 MiB
  u16* wothi  = (u16*)(R4 + 2*MiB);               // 0.5 MiB [512][512]
  u16* wotlo  = (u16*)(R4 + 2*MiB + 512*1024);    // 0.5 MiB
  u16* w1t    = (u16*)(R4 + 3*MiB);               // 8 MiB  [E][FF][D]
  u16* w2t    = (u16*)(R4 + 11*MiB);              // 8 MiB  [E][D][FF]
  // R5: small (kvs and cnt contiguous -> single memset)
  char* R5 = ws + 131*MiB;
  float* kvs    = (float*)R5;                     // 8 KB
  int*   cnt    = (int*)(R5 + 8192);              // 16 B
  float* wfull  = (float*)(R5 + 16*1024);         // 128 KB
  int*   tokl   = (int*)(R5 + 160*1024);          // 128 KB
  int*   tokslot= (int*)(R5 + 320*1024);          // 128 KB
  (void)ws_size; (void)in_sizes; (void)n_in; (void)out_size;

  dim3 tb(32, 8);

  // 0) zero kv_sum + routing counters (one memset; re-poisoned every call)
  hipMemsetAsync(kvs, 0, 8192 + 16, stream);

  // 1) operand splits / weight transposes (Wk|Wv interleaved for fused KV epilogue)
  split_f32_kernel<<<NTOK * DD / 4 / 256, 256, 0, stream>>>(x, xhi, xlo, NTOK * DD / 4);
  split_f32_kernel<<<BB * TT * TT / 4 / 256, 256, 0, stream>>>(fb, fbhi, fblo, BB * TT * TT / 4);
  transpose_split3_kernel<<<dim3(16, 16, 3), tb, 0, stream>>>(Wk, Wv, Wo,
                                                              wkvthi, wkvtlo, wothi, wotlo);
  transpose_cast_kernel<<<dim3(FFF/32, DD/32, NEXP), tb, 0, stream>>>(W1, w1t, DD, FFF);
  transpose_cast_kernel<<<dim3(DD/32, FFF/32, NEXP), tb, 0, stream>>>(W2, w2t, FFF, DD);

  // 2) fused KV: computes K,V projections; epilogue -> kv_sum atomics + V^T hi/lo.
  //    K is never written to memory. grid(64,16).
  gemm_split2_kernel<1><<<dim3(64, 16, 1), 256, 0, stream>>>(
      xhi, xlo, wkvthi, wkvtlo, bk, bv, kvs, vthi, vtlo,
      NTOK, 2*DD, DD, 0, 0, 0);

  // 3) wv[b] = fb[b]@V[b] + kv_sum[b]  (split, dbuf, hi/lo epilogue; per-batch XCD decode)
  gemm_split2_kernel<2><<<dim3(512, 1, 1), 256, 0, stream>>>(
      fbhi, fblo, vthi, vtlo, kvs, nullptr, nullptr, wvhi, wvlo,
      TT, DD, TT, (long long)TT*TT, (long long)DD*TT, (long long)TT*DD);

  // 4) attn = wv@Wo + bo  (split, f32 out; vt region dead -> attn lives there)
  gemm_split2_kernel<0><<<dim3(64, 8, 1), 256, 0, stream>>>(
      wvhi, wvlo, wothi, wotlo, bo, nullptr, attn, nullptr, nullptr,
      NTOK, DD, DD, 0, 0, 0);

  // 5) x1 = LN1(x + attn); x1b overwrites wv region (dead)
  ln_kernel<<<NTOK, 256, 0, stream>>>(x, attn, ln1g, ln1b, x1f, x1b);

  // 6) gate -> weights + per-expert token lists + per-token slot records
  gate_kernel<<<NTOK / 64, 256, 0, stream>>>(x1f, Wg, bg, wfull, tokl, cnt, tokslot);

  // 7) sparse top-2 MoE, z-fused, atomic-free: GEMM1 (1-buf) -> h, GEMM2 (depth-2 pipe) -> y
  moe_gemm1_kernel<<<dim3(NTOK/128, FFF/128, NEXP), 256, 0, stream>>>(
      x1b, tokl, cnt, w1t, b1, h);
  moe_gemm2_kernel<<<dim3(NTOK/128, DD/128, NEXP), 256, 0, stream>>>(
      h, tokl, cnt, w2t, b2, wfull, yb);

  // 8) out = LN2(x1 + y[slot0] + y[slot1])
  ln2_kernel<<<NTOK, 256, 0, stream>>>(x1f, yb, tokslot, cnt, ln2g, ln2b, (float*)d_out);
}